// Round 5
// baseline (235.100 us; speedup 1.0000x reference)
//
#include <hip/hip_runtime.h>

typedef __attribute__((ext_vector_type(8))) short short8;
typedef __attribute__((ext_vector_type(8))) unsigned short ushort8;
typedef __attribute__((ext_vector_type(4))) unsigned short ushort4v;
typedef __attribute__((ext_vector_type(4))) float f32x4;

#define DEV static __device__ __forceinline__

DEV unsigned short f2bf(float f) {
  unsigned u = __builtin_bit_cast(unsigned, f);
  u += 0x7fffu + ((u >> 16) & 1u);
  return (unsigned short)(u >> 16);
}

DEV float bf2f(unsigned short u) {
  return __builtin_bit_cast(float, (unsigned)u << 16);
}

DEV void gload_lds16(const void* g, void* l) {
  __builtin_amdgcn_global_load_lds((__attribute__((address_space(1))) void*)g,
                                   (__attribute__((address_space(3))) void*)l,
                                   16, 0, 0);
}

// ---------------------------------------------------------------------------
// fp32 -> bf16 convert (vectorized, exact-size launch)
// ---------------------------------------------------------------------------
__global__ void f2bf_k(const float4* __restrict__ in, ushort4v* __restrict__ out, int n4) {
  int i = blockIdx.x * 256 + threadIdx.x;
  if (i < n4) {
    float4 v = in[i];
    ushort4v u = { f2bf(v.x), f2bf(v.y), f2bf(v.z), f2bf(v.w) };
    out[i] = u;
  }
}

__global__ void pack_bias_k(const float* __restrict__ bq, const float* __restrict__ bk,
                            const float* __restrict__ bv, float* __restrict__ o) {
  int i = threadIdx.x;  // 512 threads
  o[i] = bq[i];
  o[512 + i] = bk[i];
  o[1024 + i] = bv[i];
}

// ---------------------------------------------------------------------------
// GEMM: C[m][n] = sum_k A[m][k] * Bw[n][k]  (A [M][K] bf16; Bw [N][K] bf16)
// 128x128 tile, BK=32, 4 waves, m97 structure.
// EPI 0: QKV scatter. Q (scaled by log2e/8) -> [bh][s][d], K -> [bh][s][d],
//        V -> TRANSPOSED [bh][d][s] via LDS-transpose (coalesced stores).
// EPI 1: bf16 out + bf16 residual (outb = bf16(acc + bias + residb))
// EPI 2: ReLU -> bf16 (outb)
// EPI 3: fp32 out + bf16 residual (outf = acc + bias + residb)
// ---------------------------------------------------------------------------
template <int EPI>
__global__ __launch_bounds__(256) void gemm_bt(
    const unsigned short* __restrict__ A, const unsigned short* __restrict__ Bw,
    const float* __restrict__ bias, int M, int N, int K,
    unsigned short* __restrict__ outb, float* __restrict__ outf,
    const unsigned short* __restrict__ residb) {
  __shared__ __align__(16) unsigned short As[128 * 32];
  __shared__ __align__(16) unsigned short Bs[128 * 32];
  const int tid = threadIdx.x;
  const int lane = tid & 63;
  const int wv = tid >> 6;
  const int wr = wv >> 1, wc = wv & 1;
  const int lrow = lane & 15, lgrp = lane >> 4;
  const int bm = blockIdx.x * 128;
  const int bn = blockIdx.y * 128;

  f32x4 acc[4][4];
#pragma unroll
  for (int m = 0; m < 4; m++)
#pragma unroll
    for (int n = 0; n < 4; n++) acc[m][n] = (f32x4){0.f, 0.f, 0.f, 0.f};

  for (int k0 = 0; k0 < K; k0 += 32) {
    __syncthreads();
#pragma unroll
    for (int i = 0; i < 2; i++) {
      const int sb = wv * 64 + i * 256;   // wave-uniform LDS slot base
      const int slot = sb + lane;
      const int row = slot >> 2, c8 = slot & 3;
      gload_lds16(A + (size_t)(bm + row) * K + k0 + c8 * 8, &As[sb * 8]);
      gload_lds16(Bw + (size_t)(bn + row) * K + k0 + c8 * 8, &Bs[sb * 8]);
    }
    __syncthreads();

    short8 af[4], bfr[4];
#pragma unroll
    for (int m = 0; m < 4; m++)
      af[m] = *(const short8*)&As[(wr * 64 + m * 16 + lrow) * 32 + lgrp * 8];
#pragma unroll
    for (int n = 0; n < 4; n++)
      bfr[n] = *(const short8*)&Bs[(wc * 64 + n * 16 + lrow) * 32 + lgrp * 8];
#pragma unroll
    for (int m = 0; m < 4; m++)
#pragma unroll
      for (int n = 0; n < 4; n++)
        acc[m][n] = __builtin_amdgcn_mfma_f32_16x16x32_bf16(af[m], bfr[n], acc[m][n], 0, 0, 0);
  }

  if constexpr (EPI == 0) {
    const int proj = bn >> 9;  // block-uniform: 0=Q, 1=K, 2=V
    if (proj == 2) {
      // --- V: transpose 128x128 tile via LDS, store [bh][d][s] coalesced ---
      __shared__ __align__(16) unsigned short VT[128 * 136];
#pragma unroll
      for (int n = 0; n < 4; n++) {
        const int cl = wc * 64 + n * 16 + lrow;  // local col (d-direction)
        const float bval = bias[bn + cl];
#pragma unroll
        for (int m = 0; m < 4; m++)
#pragma unroll
          for (int r = 0; r < 4; r++)
            VT[cl * 136 + wr * 64 + m * 16 + lgrp * 4 + r] = f2bf(acc[m][n][r] + bval);
      }
      __syncthreads();
      const int j = (bn - 1024) >> 7;   // 0..3
      const int b = bm >> 11;
      const int sbase = bm & 2047;
      unsigned short* vout = outb + (size_t)2 * 4194304;
#pragma unroll
      for (int q = 0; q < 8; q++) {
        const int chunk = q * 256 + tid;       // 2048 chunks of 8 elems
        const int cl = chunk >> 4, s8 = chunk & 15;
        const int head = 2 * j + (cl >> 6), d = cl & 63;
        ushort8 val = *(const ushort8*)&VT[cl * 136 + s8 * 8];
        *(ushort8*)(vout + ((size_t)(b * 8 + head) * 64 + d) * 2048 + sbase + s8 * 8) = val;
      }
    } else {
      const float qs = (proj == 0) ? 0.18033688011f : 1.0f;  // log2(e)/8
#pragma unroll
      for (int m = 0; m < 4; m++) {
#pragma unroll
        for (int n = 0; n < 4; n++) {
          const int gcol = bn + wc * 64 + n * 16 + lrow;
          const float bval = bias[gcol];
          const int feat = gcol & 511;
          const int head = feat >> 6, d = feat & 63;
#pragma unroll
          for (int r = 0; r < 4; r++) {
            const int grow = bm + wr * 64 + m * 16 + lgrp * 4 + r;
            const int b = grow >> 11, s = grow & 2047;
            const int bh = b * 8 + head;
            outb[(size_t)proj * 4194304 + ((size_t)bh * 2048 + s) * 64 + d] =
                f2bf((acc[m][n][r] + bval) * qs);
          }
        }
      }
    }
  } else {
#pragma unroll
    for (int m = 0; m < 4; m++) {
#pragma unroll
      for (int n = 0; n < 4; n++) {
        const int gcol = bn + wc * 64 + n * 16 + lrow;
        const float bval = bias[gcol];
#pragma unroll
        for (int r = 0; r < 4; r++) {
          const int grow = bm + wr * 64 + m * 16 + lgrp * 4 + r;
          float v = acc[m][n][r] + bval;
          const size_t o = (size_t)grow * N + gcol;
          if constexpr (EPI == 1) {
            outb[o] = f2bf(v + bf2f(residb[o]));
          } else if constexpr (EPI == 2) {
            outb[o] = f2bf(v > 0.f ? v : 0.f);
          } else {
            outf[o] = v + bf2f(residb[o]);
          }
        }
      }
    }
  }
}

// ---------------------------------------------------------------------------
// Flash attention v4: no-max softmax; double-buffered K/V staging with
// prefetch-before-compute (loads for tile t+1 in flight during tile t's
// QK^T/softmax/PV; single barrier per tile).
// Q,K in [B*NH][2048][64] bf16 (Q pre-scaled by log2e/8); V pre-transposed
// [B*NH][64][2048] bf16. Output [B*2048][512] bf16.
// ---------------------------------------------------------------------------
__global__ __launch_bounds__(256) void attn_k(
    const unsigned short* __restrict__ Qg, const unsigned short* __restrict__ Kg,
    const unsigned short* __restrict__ Vg, unsigned short* __restrict__ Og) {
  __shared__ __align__(16) unsigned short Kl[2][64 * 64];
  __shared__ __align__(16) unsigned short Vl[2][64 * 64];
  __shared__ __align__(16) unsigned short Pl[4][16 * 88];
  const int tid = threadIdx.x, lane = tid & 63, wq = tid >> 6;
  const int lrow = lane & 15, lgrp = lane >> 4;
  // XCD-chunked swizzle: 1024 blocks, 8 XCDs -> 128 consecutive per XCD
  const int bid = blockIdx.x;
  const int lin = (bid & 7) * 128 + (bid >> 3);
  const int bh = lin >> 5;         // head (4 consecutive heads per XCD)
  const int q0 = (lin & 31) * 64;  // q-block sweeps inner
  const size_t hbase = (size_t)bh * (2048 * 64);

  // staging geometry (per-thread, loop-invariant)
  const int sb0 = wq * 64;           // i=0 slot base
  const int sb1 = wq * 64 + 256;     // i=1 slot base
  const int r0 = (sb0 + lane) >> 3, c0 = ((sb0 + lane) & 7) ^ (r0 & 7);
  const int r1 = (sb1 + lane) >> 3, c1 = ((sb1 + lane) & 7) ^ (r1 & 7);

  short8 qf[2];
  {
    const unsigned short* qp = Qg + hbase + (size_t)(q0 + wq * 16 + lrow) * 64 + lgrp * 8;
    qf[0] = *(const short8*)qp;
    qf[1] = *(const short8*)(qp + 32);
  }

  f32x4 oacc[4];
#pragma unroll
  for (int f = 0; f < 4; f++) oacc[f] = (f32x4){0.f, 0.f, 0.f, 0.f};
  float lr[4] = {0.f, 0.f, 0.f, 0.f};

  // prologue: stage tile 0 into buffer 0
  {
    gload_lds16(Kg + hbase + (size_t)r0 * 64 + c0 * 8, &Kl[0][sb0 * 8]);
    gload_lds16(Vg + hbase + (size_t)r0 * 2048 + c0 * 8, &Vl[0][sb0 * 8]);
    gload_lds16(Kg + hbase + (size_t)r1 * 64 + c1 * 8, &Kl[0][sb1 * 8]);
    gload_lds16(Vg + hbase + (size_t)r1 * 2048 + c1 * 8, &Vl[0][sb1 * 8]);
  }
  __syncthreads();

  for (int it = 0; it < 32; ++it) {
    const int cur = it & 1;
    if (it < 31) {
      const int kt = (it + 1) * 64;
      const int nxt = cur ^ 1;
      gload_lds16(Kg + hbase + (size_t)(kt + r0) * 64 + c0 * 8, &Kl[nxt][sb0 * 8]);
      gload_lds16(Vg + hbase + (size_t)r0 * 2048 + kt + c0 * 8, &Vl[nxt][sb0 * 8]);
      gload_lds16(Kg + hbase + (size_t)(kt + r1) * 64 + c1 * 8, &Kl[nxt][sb1 * 8]);
      gload_lds16(Vg + hbase + (size_t)r1 * 2048 + kt + c1 * 8, &Vl[nxt][sb1 * 8]);
    }

    f32x4 sc[4];
#pragma unroll
    for (int f = 0; f < 4; f++) sc[f] = (f32x4){0.f, 0.f, 0.f, 0.f};
    __builtin_amdgcn_s_setprio(1);
#pragma unroll
    for (int f = 0; f < 4; f++) {
      const int r = f * 16 + lrow;
      short8 k0f = *(const short8*)&Kl[cur][(r * 8 + (lgrp ^ (r & 7))) * 8];
      short8 k1f = *(const short8*)&Kl[cur][(r * 8 + ((4 | lgrp) ^ (r & 7))) * 8];
      sc[f] = __builtin_amdgcn_mfma_f32_16x16x32_bf16(qf[0], k0f, sc[f], 0, 0, 0);
      sc[f] = __builtin_amdgcn_mfma_f32_16x16x32_bf16(qf[1], k1f, sc[f], 0, 0, 0);
    }
    __builtin_amdgcn_s_setprio(0);

    // p = 2^s (Q carries the 1/8*log2e scale); lane-local sum; pack pairs.
#pragma unroll
    for (int fp = 0; fp < 4; fp += 2) {
#pragma unroll
      for (int r = 0; r < 4; r++) {
        const float p0 = __builtin_amdgcn_exp2f(sc[fp][r]);
        const float p1 = __builtin_amdgcn_exp2f(sc[fp + 1][r]);
        lr[r] += p0 + p1;
        unsigned u;
        asm("v_cvt_pk_bf16_f32 %0, %1, %2" : "=v"(u) : "v"(p0), "v"(p1));
        Pl[wq][(lgrp * 4 + r) * 88 + lrow + 16 * fp] = (unsigned short)(u & 0xffffu);
        Pl[wq][(lgrp * 4 + r) * 88 + lrow + 16 * (fp + 1)] = (unsigned short)(u >> 16);
      }
    }

    short8 pa0 = *(const short8*)&Pl[wq][lrow * 88 + lgrp * 8];
    short8 pa1 = *(const short8*)&Pl[wq][lrow * 88 + 32 + lgrp * 8];
    __builtin_amdgcn_s_setprio(1);
#pragma unroll
    for (int f = 0; f < 4; f++) {
      const int r = f * 16 + lrow;
      short8 vb0 = *(const short8*)&Vl[cur][(r * 8 + (lgrp ^ (r & 7))) * 8];
      short8 vb1 = *(const short8*)&Vl[cur][(r * 8 + ((4 | lgrp) ^ (r & 7))) * 8];
      oacc[f] = __builtin_amdgcn_mfma_f32_16x16x32_bf16(pa0, vb0, oacc[f], 0, 0, 0);
      oacc[f] = __builtin_amdgcn_mfma_f32_16x16x32_bf16(pa1, vb1, oacc[f], 0, 0, 0);
    }
    __builtin_amdgcn_s_setprio(0);

    __syncthreads();  // next-tile loads complete + all waves done with cur
  }

  // one cross-lane sum reduce (lanes lrow 0..15 within each lgrp group)
  float inv[4];
#pragma unroll
  for (int r = 0; r < 4; r++) {
    float s = lr[r];
#pragma unroll
    for (int off = 8; off >= 1; off >>= 1) s += __shfl_xor(s, off);
    inv[r] = 1.0f / s;
  }

  const int b = bh >> 3, h = bh & 7;
#pragma unroll
  for (int f = 0; f < 4; f++) {
#pragma unroll
    for (int r = 0; r < 4; r++) {
      const int row = q0 + wq * 16 + lgrp * 4 + r;
      Og[((size_t)(b * 2048 + row)) * 512 + h * 64 + f * 16 + lrow] = f2bf(oacc[f][r] * inv[r]);
    }
  }
}

// ---------------------------------------------------------------------------
// LayerNorm over last dim (512), one wave per token.
// ln_k:    fp32 in -> fp32 out (safe in-place)
// ln_bf_k: bf16 in -> bf16 out
// ---------------------------------------------------------------------------
__global__ __launch_bounds__(64) void ln_k(const float* __restrict__ in,
                                           const float* __restrict__ g,
                                           const float* __restrict__ bb,
                                           float* __restrict__ outf) {
  const int row = blockIdx.x, lane = threadIdx.x;
  const float4* p = (const float4*)(in + (size_t)row * 512);
  float4 a = p[lane], b4 = p[lane + 64];
  float s = a.x + a.y + a.z + a.w + b4.x + b4.y + b4.z + b4.w;
#pragma unroll
  for (int off = 32; off >= 1; off >>= 1) s += __shfl_xor(s, off);
  const float mu = s * (1.f / 512.f);
  float q = 0.f;
  {
    float d;
    d = a.x - mu; q += d * d; d = a.y - mu; q += d * d;
    d = a.z - mu; q += d * d; d = a.w - mu; q += d * d;
    d = b4.x - mu; q += d * d; d = b4.y - mu; q += d * d;
    d = b4.z - mu; q += d * d; d = b4.w - mu; q += d * d;
  }
#pragma unroll
  for (int off = 32; off >= 1; off >>= 1) q += __shfl_xor(q, off);
  const float rstd = rsqrtf(q * (1.f / 512.f) + 1e-5f);
  const float4* gp = (const float4*)g;
  const float4* bp = (const float4*)bb;
  float4 g0 = gp[lane], g1 = gp[lane + 64], c0 = bp[lane], c1 = bp[lane + 64];
  float4 o0, o1;
  o0.x = (a.x - mu) * rstd * g0.x + c0.x;
  o0.y = (a.y - mu) * rstd * g0.y + c0.y;
  o0.z = (a.z - mu) * rstd * g0.z + c0.z;
  o0.w = (a.w - mu) * rstd * g0.w + c0.w;
  o1.x = (b4.x - mu) * rstd * g1.x + c1.x;
  o1.y = (b4.y - mu) * rstd * g1.y + c1.y;
  o1.z = (b4.z - mu) * rstd * g1.z + c1.z;
  o1.w = (b4.w - mu) * rstd * g1.w + c1.w;
  float4* of = (float4*)(outf + (size_t)row * 512);
  of[lane] = o0;
  of[lane + 64] = o1;
}

__global__ __launch_bounds__(64) void ln_bf_k(const unsigned short* __restrict__ in,
                                              const float* __restrict__ g,
                                              const float* __restrict__ bb,
                                              unsigned short* __restrict__ out) {
  const int row = blockIdx.x, lane = threadIdx.x;
  ushort8 v = *(const ushort8*)(in + (size_t)row * 512 + lane * 8);
  float f[8];
#pragma unroll
  for (int j = 0; j < 8; j++) f[j] = bf2f(v[j]);
  float s = 0.f;
#pragma unroll
  for (int j = 0; j < 8; j++) s += f[j];
#pragma unroll
  for (int off = 32; off >= 1; off >>= 1) s += __shfl_xor(s, off);
  const float mu = s * (1.f / 512.f);
  float q = 0.f;
#pragma unroll
  for (int j = 0; j < 8; j++) { const float d = f[j] - mu; q += d * d; }
#pragma unroll
  for (int off = 32; off >= 1; off >>= 1) q += __shfl_xor(q, off);
  const float rstd = rsqrtf(q * (1.f / 512.f) + 1e-5f);
  const float4* gp = (const float4*)g;
  const float4* bp = (const float4*)bb;
  float4 g0 = gp[lane * 2], g1 = gp[lane * 2 + 1];
  float4 c0 = bp[lane * 2], c1 = bp[lane * 2 + 1];
  const float gg[8] = {g0.x, g0.y, g0.z, g0.w, g1.x, g1.y, g1.z, g1.w};
  const float cc[8] = {c0.x, c0.y, c0.z, c0.w, c1.x, c1.y, c1.z, c1.w};
  ushort8 ov;
#pragma unroll
  for (int j = 0; j < 8; j++) ov[j] = f2bf((f[j] - mu) * rstd * gg[j] + cc[j]);
  *(ushort8*)(out + (size_t)row * 512 + lane * 8) = ov;
}

// ---------------------------------------------------------------------------
extern "C" void kernel_launch(void* const* d_in, const int* in_sizes, int n_in,
                              void* d_out, int out_size, void* d_ws, size_t ws_size,
                              hipStream_t stream) {
  const float* x = (const float*)d_in[0];
  const float* wq = (const float*)d_in[1];
  const float* bq = (const float*)d_in[2];
  const float* wk = (const float*)d_in[3];
  const float* bk = (const float*)d_in[4];
  const float* wv = (const float*)d_in[5];
  const float* bv = (const float*)d_in[6];
  const float* wo = (const float*)d_in[7];
  const float* bo = (const float*)d_in[8];
  const float* ln_g = (const float*)d_in[9];
  const float* ln_b = (const float*)d_in[10];
  const float* w1 = (const float*)d_in[11];
  const float* b1 = (const float*)d_in[12];
  const float* w2 = (const float*)d_in[13];
  const float* b2 = (const float*)d_in[14];

  // workspace carve-up (ushort elems)
  unsigned short* ws_u = (unsigned short*)d_ws;
  unsigned short* wqkv = ws_u;                   // 786432
  unsigned short* wob = wqkv + 786432;           // 262144
  unsigned short* w1b = wob + 262144;            // 1048576
  unsigned short* w2b = w1b + 1048576;           // 1048576
  unsigned short* xb = w2b + 1048576;            // 4194304  [8192][512]
  unsigned short* qb = xb + 4194304;             // [32][2048][64]
  unsigned short* kb = qb + 4194304;             // [32][2048][64]
  unsigned short* vtb = kb + 4194304;            // V^T [32][64][2048]
  unsigned short* ob = vtb + 4194304;            // attn out [8192][512]
  unsigned short* s1b = ob + 4194304;            // h_pre bf16 [8192][512]
  unsigned short* hb = s1b + 4194304;            // h bf16 [8192][512]
  unsigned short* f1b = qb;                      // reuse qb..ob: [8192][2048]
  float* bqkv = (float*)(hb + 4194304);          // 1536

  auto cvt = [&](const float* src, unsigned short* dst, int n) {
    f2bf_k<<<n / 1024, 256, 0, stream>>>((const float4*)src, (ushort4v*)dst, n / 4);
  };
  cvt(wq, wqkv, 262144);
  cvt(wk, wqkv + 262144, 262144);
  cvt(wv, wqkv + 524288, 262144);
  cvt(wo, wob, 262144);
  cvt(w1, w1b, 1048576);
  cvt(w2, w2b, 1048576);
  cvt(x, xb, 4194304);
  pack_bias_k<<<1, 512, 0, stream>>>(bq, bk, bv, bqkv);

  // QKV projection: M=8192, N=1536, K=512 -> scatter into qb/kb/vtb
  gemm_bt<0><<<dim3(64, 12), 256, 0, stream>>>(xb, wqkv, bqkv, 8192, 1536, 512,
                                               qb, nullptr, nullptr);
  // attention (1024 blocks, XCD-chunked internally)
  attn_k<<<1024, 256, 0, stream>>>(qb, kb, vtb, ob);
  // O projection + residual(xb): -> s1b bf16
  gemm_bt<1><<<dim3(64, 4), 256, 0, stream>>>(ob, wob, bo, 8192, 512, 512,
                                              s1b, nullptr, xb);
  // LN1 (bf16 -> bf16)
  ln_bf_k<<<8192, 64, 0, stream>>>(s1b, ln_g, ln_b, hb);
  // FFN1 + ReLU: M=8192, N=2048, K=512 -> f1b bf16
  gemm_bt<2><<<dim3(64, 16), 256, 0, stream>>>(hb, w1b, b1, 8192, 2048, 512,
                                               f1b, nullptr, nullptr);
  // FFN2 + residual(hb): M=8192, N=512, K=2048 -> d_out fp32
  gemm_bt<3><<<dim3(64, 4), 256, 0, stream>>>(f1b, w2b, b2, 8192, 512, 2048,
                                              nullptr, (float*)d_out, hb);
  // LN2 in-place on d_out
  ln_k<<<8192, 64, 0, stream>>>((float*)d_out, ln_g, ln_b, (float*)d_out);
}

// Round 6
// 205.716 us; speedup vs baseline: 1.1428x; 1.1428x over previous
//
#include <hip/hip_runtime.h>

typedef __attribute__((ext_vector_type(8))) short short8;
typedef __attribute__((ext_vector_type(8))) unsigned short ushort8;
typedef __attribute__((ext_vector_type(4))) unsigned short ushort4v;
typedef __attribute__((ext_vector_type(4))) float f32x4;

#define DEV static __device__ __forceinline__

DEV unsigned short f2bf(float f) {
  unsigned u = __builtin_bit_cast(unsigned, f);
  u += 0x7fffu + ((u >> 16) & 1u);
  return (unsigned short)(u >> 16);
}

DEV float bf2f(unsigned short u) {
  return __builtin_bit_cast(float, (unsigned)u << 16);
}

DEV void gload_lds16(const void* g, void* l) {
  __builtin_amdgcn_global_load_lds((__attribute__((address_space(1))) void*)g,
                                   (__attribute__((address_space(3))) void*)l,
                                   16, 0, 0);
}

// ---------------------------------------------------------------------------
// fused fp32 -> bf16 convert for all 7 regions in ONE launch.
// Regions (float4 units of 4 elems, 256 units/block):
//   wq,wk,wv -> wqkv (65536 units each), wo -> wob (65536),
//   w1 -> w1b (262144), w2 -> w2b (262144), x -> xb (1048576)
// grid = 256*4 + 1024*2 + 4096 = 7168 blocks
// ---------------------------------------------------------------------------
__global__ __launch_bounds__(256) void cvt_all_k(
    const float4* __restrict__ wq, const float4* __restrict__ wk,
    const float4* __restrict__ wv, const float4* __restrict__ wo,
    const float4* __restrict__ w1, const float4* __restrict__ w2,
    const float4* __restrict__ x, ushort4v* __restrict__ wqkv,
    ushort4v* __restrict__ wob, ushort4v* __restrict__ w1b,
    ushort4v* __restrict__ w2b, ushort4v* __restrict__ xb) {
  const int i = threadIdx.x;
  const int b = blockIdx.x;
  const float4* s;
  ushort4v* d;
  size_t u;
  if (b < 256)       { s = wq; d = wqkv;          u = (size_t)b * 256 + i; }
  else if (b < 512)  { s = wk; d = wqkv + 65536;  u = (size_t)(b - 256) * 256 + i; }
  else if (b < 768)  { s = wv; d = wqkv + 131072; u = (size_t)(b - 512) * 256 + i; }
  else if (b < 1024) { s = wo; d = wob;           u = (size_t)(b - 768) * 256 + i; }
  else if (b < 2048) { s = w1; d = w1b;           u = (size_t)(b - 1024) * 256 + i; }
  else if (b < 3072) { s = w2; d = w2b;           u = (size_t)(b - 2048) * 256 + i; }
  else               { s = x;  d = xb;            u = (size_t)(b - 3072) * 256 + i; }
  float4 v = s[u];
  ushort4v o = { f2bf(v.x), f2bf(v.y), f2bf(v.z), f2bf(v.w) };
  d[u] = o;
}

__global__ void pack_bias_k(const float* __restrict__ bq, const float* __restrict__ bk,
                            const float* __restrict__ bv, float* __restrict__ o) {
  int i = threadIdx.x;  // 512 threads
  o[i] = bq[i];
  o[512 + i] = bk[i];
  o[1024 + i] = bv[i];
}

// ---------------------------------------------------------------------------
// GEMM: C[m][n] = sum_k A[m][k] * Bw[n][k]  (A [M][K] bf16; Bw [N][K] bf16)
// 128x128 tile, BK=32, 4 waves, m97 structure.
// EPI 0: QKV scatter. Q (scaled by log2e/8) -> [bh][s][d], K -> [bh][s][d],
//        V -> TRANSPOSED [bh][d][s] via LDS-transpose (coalesced stores).
// EPI 1: bf16 out + bf16 residual (outb = bf16(acc + bias + residb))
// EPI 2: ReLU -> bf16 (outb)
// EPI 3: fp32 out + bf16 residual (outf = acc + bias + residb)
// ---------------------------------------------------------------------------
template <int EPI>
__global__ __launch_bounds__(256) void gemm_bt(
    const unsigned short* __restrict__ A, const unsigned short* __restrict__ Bw,
    const float* __restrict__ bias, int M, int N, int K,
    unsigned short* __restrict__ outb, float* __restrict__ outf,
    const unsigned short* __restrict__ residb) {
  __shared__ __align__(16) unsigned short As[128 * 32];
  __shared__ __align__(16) unsigned short Bs[128 * 32];
  const int tid = threadIdx.x;
  const int lane = tid & 63;
  const int wv = tid >> 6;
  const int wr = wv >> 1, wc = wv & 1;
  const int lrow = lane & 15, lgrp = lane >> 4;
  const int bm = blockIdx.x * 128;
  const int bn = blockIdx.y * 128;

  f32x4 acc[4][4];
#pragma unroll
  for (int m = 0; m < 4; m++)
#pragma unroll
    for (int n = 0; n < 4; n++) acc[m][n] = (f32x4){0.f, 0.f, 0.f, 0.f};

  for (int k0 = 0; k0 < K; k0 += 32) {
    __syncthreads();
#pragma unroll
    for (int i = 0; i < 2; i++) {
      const int sb = wv * 64 + i * 256;   // wave-uniform LDS slot base
      const int slot = sb + lane;
      const int row = slot >> 2, c8 = slot & 3;
      gload_lds16(A + (size_t)(bm + row) * K + k0 + c8 * 8, &As[sb * 8]);
      gload_lds16(Bw + (size_t)(bn + row) * K + k0 + c8 * 8, &Bs[sb * 8]);
    }
    __syncthreads();

    short8 af[4], bfr[4];
#pragma unroll
    for (int m = 0; m < 4; m++)
      af[m] = *(const short8*)&As[(wr * 64 + m * 16 + lrow) * 32 + lgrp * 8];
#pragma unroll
    for (int n = 0; n < 4; n++)
      bfr[n] = *(const short8*)&Bs[(wc * 64 + n * 16 + lrow) * 32 + lgrp * 8];
#pragma unroll
    for (int m = 0; m < 4; m++)
#pragma unroll
      for (int n = 0; n < 4; n++)
        acc[m][n] = __builtin_amdgcn_mfma_f32_16x16x32_bf16(af[m], bfr[n], acc[m][n], 0, 0, 0);
  }

  if constexpr (EPI == 0) {
    const int proj = bn >> 9;  // block-uniform: 0=Q, 1=K, 2=V
    if (proj == 2) {
      // --- V: transpose 128x128 tile via LDS, store [bh][d][s] coalesced ---
      __shared__ __align__(16) unsigned short VT[128 * 136];
#pragma unroll
      for (int n = 0; n < 4; n++) {
        const int cl = wc * 64 + n * 16 + lrow;  // local col (d-direction)
        const float bval = bias[bn + cl];
#pragma unroll
        for (int m = 0; m < 4; m++)
#pragma unroll
          for (int r = 0; r < 4; r++)
            VT[cl * 136 + wr * 64 + m * 16 + lgrp * 4 + r] = f2bf(acc[m][n][r] + bval);
      }
      __syncthreads();
      const int j = (bn - 1024) >> 7;   // 0..3
      const int b = bm >> 11;
      const int sbase = bm & 2047;
      unsigned short* vout = outb + (size_t)2 * 4194304;
#pragma unroll
      for (int q = 0; q < 8; q++) {
        const int chunk = q * 256 + tid;       // 2048 chunks of 8 elems
        const int cl = chunk >> 4, s8 = chunk & 15;
        const int head = 2 * j + (cl >> 6), d = cl & 63;
        ushort8 val = *(const ushort8*)&VT[cl * 136 + s8 * 8];
        *(ushort8*)(vout + ((size_t)(b * 8 + head) * 64 + d) * 2048 + sbase + s8 * 8) = val;
      }
    } else {
      const float qs = (proj == 0) ? 0.18033688011f : 1.0f;  // log2(e)/8
#pragma unroll
      for (int m = 0; m < 4; m++) {
#pragma unroll
        for (int n = 0; n < 4; n++) {
          const int gcol = bn + wc * 64 + n * 16 + lrow;
          const float bval = bias[gcol];
          const int feat = gcol & 511;
          const int head = feat >> 6, d = feat & 63;
#pragma unroll
          for (int r = 0; r < 4; r++) {
            const int grow = bm + wr * 64 + m * 16 + lgrp * 4 + r;
            const int b = grow >> 11, s = grow & 2047;
            const int bh = b * 8 + head;
            outb[(size_t)proj * 4194304 + ((size_t)bh * 2048 + s) * 64 + d] =
                f2bf((acc[m][n][r] + bval) * qs);
          }
        }
      }
    }
  } else {
#pragma unroll
    for (int m = 0; m < 4; m++) {
#pragma unroll
      for (int n = 0; n < 4; n++) {
        const int gcol = bn + wc * 64 + n * 16 + lrow;
        const float bval = bias[gcol];
#pragma unroll
        for (int r = 0; r < 4; r++) {
          const int grow = bm + wr * 64 + m * 16 + lgrp * 4 + r;
          float v = acc[m][n][r] + bval;
          const size_t o = (size_t)grow * N + gcol;
          if constexpr (EPI == 1) {
            outb[o] = f2bf(v + bf2f(residb[o]));
          } else if constexpr (EPI == 2) {
            outb[o] = f2bf(v > 0.f ? v : 0.f);
          } else {
            outf[o] = v + bf2f(residb[o]);
          }
        }
      }
    }
  }
}

// ---------------------------------------------------------------------------
// Flash attention (round-4 structure): no-max softmax; single-buffer K/V
// staged via global_load_lds with XOR chunk swizzle.
// Q,K in [B*NH][2048][64] bf16 (Q pre-scaled by log2e/8); V pre-transposed
// [B*NH][64][2048] bf16. Output [B*2048][512] bf16.
// ---------------------------------------------------------------------------
__global__ __launch_bounds__(256) void attn_k(
    const unsigned short* __restrict__ Qg, const unsigned short* __restrict__ Kg,
    const unsigned short* __restrict__ Vg, unsigned short* __restrict__ Og) {
  __shared__ __align__(16) unsigned short Kl[64 * 64];
  __shared__ __align__(16) unsigned short Vl[64 * 64];
  __shared__ __align__(16) unsigned short Pl[4][16 * 88];
  const int tid = threadIdx.x, lane = tid & 63, wq = tid >> 6;
  const int lrow = lane & 15, lgrp = lane >> 4;
  // XCD-chunked swizzle: 1024 blocks, 8 XCDs -> 128 consecutive per XCD
  const int bid = blockIdx.x;
  const int lin = (bid & 7) * 128 + (bid >> 3);
  const int bh = lin >> 5;         // head (4 consecutive heads per XCD)
  const int q0 = (lin & 31) * 64;  // q-block sweeps inner
  const size_t hbase = (size_t)bh * (2048 * 64);

  short8 qf[2];
  {
    const unsigned short* qp = Qg + hbase + (size_t)(q0 + wq * 16 + lrow) * 64 + lgrp * 8;
    qf[0] = *(const short8*)qp;
    qf[1] = *(const short8*)(qp + 32);
  }

  f32x4 oacc[4];
#pragma unroll
  for (int f = 0; f < 4; f++) oacc[f] = (f32x4){0.f, 0.f, 0.f, 0.f};
  float lr[4] = {0.f, 0.f, 0.f, 0.f};

  for (int kt = 0; kt < 2048; kt += 64) {
    __syncthreads();
    // stage K tile [64 k][64 d] and V^T tile [64 d][64 k-slice]; chunk at LDS
    // slot p holds global chunk (r = p>>3, c = (p&7)^(r&7)) -> ds_read ~2-way.
#pragma unroll
    for (int i = 0; i < 2; i++) {
      const int sb = wq * 64 + i * 256;   // wave-uniform LDS slot base
      const int slot = sb + lane;
      const int r = slot >> 3;
      const int c = (slot & 7) ^ (r & 7);
      gload_lds16(Kg + hbase + (size_t)(kt + r) * 64 + c * 8, &Kl[sb * 8]);
      gload_lds16(Vg + hbase + (size_t)r * 2048 + kt + c * 8, &Vl[sb * 8]);
    }
    __syncthreads();

    f32x4 sc[4];
#pragma unroll
    for (int f = 0; f < 4; f++) sc[f] = (f32x4){0.f, 0.f, 0.f, 0.f};
    __builtin_amdgcn_s_setprio(1);
#pragma unroll
    for (int f = 0; f < 4; f++) {
      const int r = f * 16 + lrow;
      short8 k0f = *(const short8*)&Kl[(r * 8 + (lgrp ^ (r & 7))) * 8];
      short8 k1f = *(const short8*)&Kl[(r * 8 + ((4 | lgrp) ^ (r & 7))) * 8];
      sc[f] = __builtin_amdgcn_mfma_f32_16x16x32_bf16(qf[0], k0f, sc[f], 0, 0, 0);
      sc[f] = __builtin_amdgcn_mfma_f32_16x16x32_bf16(qf[1], k1f, sc[f], 0, 0, 0);
    }
    __builtin_amdgcn_s_setprio(0);

    // p = 2^s (Q carries the 1/8*log2e scale); lane-local sum; pack pairs.
#pragma unroll
    for (int fp = 0; fp < 4; fp += 2) {
#pragma unroll
      for (int r = 0; r < 4; r++) {
        const float p0 = __builtin_amdgcn_exp2f(sc[fp][r]);
        const float p1 = __builtin_amdgcn_exp2f(sc[fp + 1][r]);
        lr[r] += p0 + p1;
        unsigned u;
        asm("v_cvt_pk_bf16_f32 %0, %1, %2" : "=v"(u) : "v"(p0), "v"(p1));
        Pl[wq][(lgrp * 4 + r) * 88 + lrow + 16 * fp] = (unsigned short)(u & 0xffffu);
        Pl[wq][(lgrp * 4 + r) * 88 + lrow + 16 * (fp + 1)] = (unsigned short)(u >> 16);
      }
    }

    short8 pa0 = *(const short8*)&Pl[wq][lrow * 88 + lgrp * 8];
    short8 pa1 = *(const short8*)&Pl[wq][lrow * 88 + 32 + lgrp * 8];
    __builtin_amdgcn_s_setprio(1);
#pragma unroll
    for (int f = 0; f < 4; f++) {
      const int r = f * 16 + lrow;
      short8 vb0 = *(const short8*)&Vl[(r * 8 + (lgrp ^ (r & 7))) * 8];
      short8 vb1 = *(const short8*)&Vl[(r * 8 + ((4 | lgrp) ^ (r & 7))) * 8];
      oacc[f] = __builtin_amdgcn_mfma_f32_16x16x32_bf16(pa0, vb0, oacc[f], 0, 0, 0);
      oacc[f] = __builtin_amdgcn_mfma_f32_16x16x32_bf16(pa1, vb1, oacc[f], 0, 0, 0);
    }
    __builtin_amdgcn_s_setprio(0);
  }

  // one cross-lane sum reduce (lanes lrow 0..15 within each lgrp group)
  float inv[4];
#pragma unroll
  for (int r = 0; r < 4; r++) {
    float s = lr[r];
#pragma unroll
    for (int off = 8; off >= 1; off >>= 1) s += __shfl_xor(s, off);
    inv[r] = 1.0f / s;
  }

  const int b = bh >> 3, h = bh & 7;
#pragma unroll
  for (int f = 0; f < 4; f++) {
#pragma unroll
    for (int r = 0; r < 4; r++) {
      const int row = q0 + wq * 16 + lgrp * 4 + r;
      Og[((size_t)(b * 2048 + row)) * 512 + h * 64 + f * 16 + lrow] = f2bf(oacc[f][r] * inv[r]);
    }
  }
}

// ---------------------------------------------------------------------------
// LayerNorm over last dim (512), one wave per token.
// ln_k:    fp32 in -> fp32 out (safe in-place)
// ln_bf_k: bf16 in -> bf16 out
// ---------------------------------------------------------------------------
__global__ __launch_bounds__(64) void ln_k(const float* __restrict__ in,
                                           const float* __restrict__ g,
                                           const float* __restrict__ bb,
                                           float* __restrict__ outf) {
  const int row = blockIdx.x, lane = threadIdx.x;
  const float4* p = (const float4*)(in + (size_t)row * 512);
  float4 a = p[lane], b4 = p[lane + 64];
  float s = a.x + a.y + a.z + a.w + b4.x + b4.y + b4.z + b4.w;
#pragma unroll
  for (int off = 32; off >= 1; off >>= 1) s += __shfl_xor(s, off);
  const float mu = s * (1.f / 512.f);
  float q = 0.f;
  {
    float d;
    d = a.x - mu; q += d * d; d = a.y - mu; q += d * d;
    d = a.z - mu; q += d * d; d = a.w - mu; q += d * d;
    d = b4.x - mu; q += d * d; d = b4.y - mu; q += d * d;
    d = b4.z - mu; q += d * d; d = b4.w - mu; q += d * d;
  }
#pragma unroll
  for (int off = 32; off >= 1; off >>= 1) q += __shfl_xor(q, off);
  const float rstd = rsqrtf(q * (1.f / 512.f) + 1e-5f);
  const float4* gp = (const float4*)g;
  const float4* bp = (const float4*)bb;
  float4 g0 = gp[lane], g1 = gp[lane + 64], c0 = bp[lane], c1 = bp[lane + 64];
  float4 o0, o1;
  o0.x = (a.x - mu) * rstd * g0.x + c0.x;
  o0.y = (a.y - mu) * rstd * g0.y + c0.y;
  o0.z = (a.z - mu) * rstd * g0.z + c0.z;
  o0.w = (a.w - mu) * rstd * g0.w + c0.w;
  o1.x = (b4.x - mu) * rstd * g1.x + c1.x;
  o1.y = (b4.y - mu) * rstd * g1.y + c1.y;
  o1.z = (b4.z - mu) * rstd * g1.z + c1.z;
  o1.w = (b4.w - mu) * rstd * g1.w + c1.w;
  float4* of = (float4*)(outf + (size_t)row * 512);
  of[lane] = o0;
  of[lane + 64] = o1;
}

__global__ __launch_bounds__(64) void ln_bf_k(const unsigned short* __restrict__ in,
                                              const float* __restrict__ g,
                                              const float* __restrict__ bb,
                                              unsigned short* __restrict__ out) {
  const int row = blockIdx.x, lane = threadIdx.x;
  ushort8 v = *(const ushort8*)(in + (size_t)row * 512 + lane * 8);
  float f[8];
#pragma unroll
  for (int j = 0; j < 8; j++) f[j] = bf2f(v[j]);
  float s = 0.f;
#pragma unroll
  for (int j = 0; j < 8; j++) s += f[j];
#pragma unroll
  for (int off = 32; off >= 1; off >>= 1) s += __shfl_xor(s, off);
  const float mu = s * (1.f / 512.f);
  float q = 0.f;
#pragma unroll
  for (int j = 0; j < 8; j++) { const float d = f[j] - mu; q += d * d; }
#pragma unroll
  for (int off = 32; off >= 1; off >>= 1) q += __shfl_xor(q, off);
  const float rstd = rsqrtf(q * (1.f / 512.f) + 1e-5f);
  const float4* gp = (const float4*)g;
  const float4* bp = (const float4*)bb;
  float4 g0 = gp[lane * 2], g1 = gp[lane * 2 + 1];
  float4 c0 = bp[lane * 2], c1 = bp[lane * 2 + 1];
  const float gg[8] = {g0.x, g0.y, g0.z, g0.w, g1.x, g1.y, g1.z, g1.w};
  const float cc[8] = {c0.x, c0.y, c0.z, c0.w, c1.x, c1.y, c1.z, c1.w};
  ushort8 ov;
#pragma unroll
  for (int j = 0; j < 8; j++) ov[j] = f2bf((f[j] - mu) * rstd * gg[j] + cc[j]);
  *(ushort8*)(out + (size_t)row * 512 + lane * 8) = ov;
}

// ---------------------------------------------------------------------------
extern "C" void kernel_launch(void* const* d_in, const int* in_sizes, int n_in,
                              void* d_out, int out_size, void* d_ws, size_t ws_size,
                              hipStream_t stream) {
  const float* x = (const float*)d_in[0];
  const float* wq = (const float*)d_in[1];
  const float* bq = (const float*)d_in[2];
  const float* wk = (const float*)d_in[3];
  const float* bk = (const float*)d_in[4];
  const float* wv = (const float*)d_in[5];
  const float* bv = (const float*)d_in[6];
  const float* wo = (const float*)d_in[7];
  const float* bo = (const float*)d_in[8];
  const float* ln_g = (const float*)d_in[9];
  const float* ln_b = (const float*)d_in[10];
  const float* w1 = (const float*)d_in[11];
  const float* b1 = (const float*)d_in[12];
  const float* w2 = (const float*)d_in[13];
  const float* b2 = (const float*)d_in[14];

  // workspace carve-up (ushort elems)
  unsigned short* ws_u = (unsigned short*)d_ws;
  unsigned short* wqkv = ws_u;                   // 786432
  unsigned short* wob = wqkv + 786432;           // 262144
  unsigned short* w1b = wob + 262144;            // 1048576
  unsigned short* w2b = w1b + 1048576;           // 1048576
  unsigned short* xb = w2b + 1048576;            // 4194304  [8192][512]
  unsigned short* qb = xb + 4194304;             // [32][2048][64]
  unsigned short* kb = qb + 4194304;             // [32][2048][64]
  unsigned short* vtb = kb + 4194304;            // V^T [32][64][2048]
  unsigned short* ob = vtb + 4194304;            // attn out [8192][512]
  unsigned short* s1b = ob + 4194304;            // h_pre bf16 [8192][512]
  unsigned short* hb = s1b + 4194304;            // h bf16 [8192][512]
  unsigned short* f1b = qb;                      // reuse qb..ob: [8192][2048]
  float* bqkv = (float*)(hb + 4194304);          // 1536

  // one fused convert launch for all weights + x
  cvt_all_k<<<7168, 256, 0, stream>>>(
      (const float4*)wq, (const float4*)wk, (const float4*)wv, (const float4*)wo,
      (const float4*)w1, (const float4*)w2, (const float4*)x,
      (ushort4v*)wqkv, (ushort4v*)wob, (ushort4v*)w1b, (ushort4v*)w2b,
      (ushort4v*)xb);
  pack_bias_k<<<1, 512, 0, stream>>>(bq, bk, bv, bqkv);

  // QKV projection: M=8192, N=1536, K=512 -> scatter into qb/kb/vtb
  gemm_bt<0><<<dim3(64, 12), 256, 0, stream>>>(xb, wqkv, bqkv, 8192, 1536, 512,
                                               qb, nullptr, nullptr);
  // attention (1024 blocks, XCD-chunked internally)
  attn_k<<<1024, 256, 0, stream>>>(qb, kb, vtb, ob);
  // O projection + residual(xb): -> s1b bf16
  gemm_bt<1><<<dim3(64, 4), 256, 0, stream>>>(ob, wob, bo, 8192, 512, 512,
                                              s1b, nullptr, xb);
  // LN1 (bf16 -> bf16)
  ln_bf_k<<<8192, 64, 0, stream>>>(s1b, ln_g, ln_b, hb);
  // FFN1 + ReLU: M=8192, N=2048, K=512 -> f1b bf16
  gemm_bt<2><<<dim3(64, 16), 256, 0, stream>>>(hb, w1b, b1, 8192, 2048, 512,
                                               f1b, nullptr, nullptr);
  // FFN2 + residual(hb): M=8192, N=512, K=2048 -> d_out fp32
  gemm_bt<3><<<dim3(64, 4), 256, 0, stream>>>(f1b, w2b, b2, 8192, 512, 2048,
                                              nullptr, (float*)d_out, hb);
  // LN2 in-place on d_out
  ln_k<<<8192, 64, 0, stream>>>((float*)d_out, ln_g, ln_b, (float*)d_out);
}

// Round 7
// 196.656 us; speedup vs baseline: 1.1955x; 1.0461x over previous
//
#include <hip/hip_runtime.h>

typedef __attribute__((ext_vector_type(8))) short short8;
typedef __attribute__((ext_vector_type(8))) unsigned short ushort8;
typedef __attribute__((ext_vector_type(4))) unsigned short ushort4v;
typedef __attribute__((ext_vector_type(4))) float f32x4;

#define DEV static __device__ __forceinline__

DEV unsigned short f2bf(float f) {
  unsigned u = __builtin_bit_cast(unsigned, f);
  u += 0x7fffu + ((u >> 16) & 1u);
  return (unsigned short)(u >> 16);
}

DEV float bf2f(unsigned short u) {
  return __builtin_bit_cast(float, (unsigned)u << 16);
}

DEV void gload_lds16(const void* g, void* l) {
  __builtin_amdgcn_global_load_lds((__attribute__((address_space(1))) void*)g,
                                   (__attribute__((address_space(3))) void*)l,
                                   16, 0, 0);
}

// ---------------------------------------------------------------------------
// fused fp32 -> bf16 convert for all 7 regions in ONE launch.
// ---------------------------------------------------------------------------
__global__ __launch_bounds__(256) void cvt_all_k(
    const float4* __restrict__ wq, const float4* __restrict__ wk,
    const float4* __restrict__ wv, const float4* __restrict__ wo,
    const float4* __restrict__ w1, const float4* __restrict__ w2,
    const float4* __restrict__ x, ushort4v* __restrict__ wqkv,
    ushort4v* __restrict__ wob, ushort4v* __restrict__ w1b,
    ushort4v* __restrict__ w2b, ushort4v* __restrict__ xb) {
  const int i = threadIdx.x;
  const int b = blockIdx.x;
  const float4* s;
  ushort4v* d;
  size_t u;
  if (b < 256)       { s = wq; d = wqkv;          u = (size_t)b * 256 + i; }
  else if (b < 512)  { s = wk; d = wqkv + 65536;  u = (size_t)(b - 256) * 256 + i; }
  else if (b < 768)  { s = wv; d = wqkv + 131072; u = (size_t)(b - 512) * 256 + i; }
  else if (b < 1024) { s = wo; d = wob;           u = (size_t)(b - 768) * 256 + i; }
  else if (b < 2048) { s = w1; d = w1b;           u = (size_t)(b - 1024) * 256 + i; }
  else if (b < 3072) { s = w2; d = w2b;           u = (size_t)(b - 2048) * 256 + i; }
  else               { s = x;  d = xb;            u = (size_t)(b - 3072) * 256 + i; }
  float4 v = s[u];
  ushort4v o = { f2bf(v.x), f2bf(v.y), f2bf(v.z), f2bf(v.w) };
  d[u] = o;
}

__global__ void pack_bias_k(const float* __restrict__ bq, const float* __restrict__ bk,
                            const float* __restrict__ bv, float* __restrict__ o) {
  int i = threadIdx.x;  // 512 threads
  o[i] = bq[i];
  o[512 + i] = bk[i];
  o[1024 + i] = bv[i];
}

// ---------------------------------------------------------------------------
// GEMM 128x128 (m97 structure), BK=32, 4 waves.
// EPI 0: QKV scatter. Q (scaled by log2e/8) -> [bh][s][d], K -> [bh][s][d],
//        V -> TRANSPOSED [bh][d][s] via LDS-transpose (coalesced stores).
// EPI 2: ReLU -> bf16 (outb)
// ---------------------------------------------------------------------------
template <int EPI>
__global__ __launch_bounds__(256) void gemm_bt(
    const unsigned short* __restrict__ A, const unsigned short* __restrict__ Bw,
    const float* __restrict__ bias, int M, int N, int K,
    unsigned short* __restrict__ outb, float* __restrict__ outf,
    const unsigned short* __restrict__ residb) {
  __shared__ __align__(16) unsigned short As[128 * 32];
  __shared__ __align__(16) unsigned short Bs[128 * 32];
  const int tid = threadIdx.x;
  const int lane = tid & 63;
  const int wv = tid >> 6;
  const int wr = wv >> 1, wc = wv & 1;
  const int lrow = lane & 15, lgrp = lane >> 4;
  const int bm = blockIdx.x * 128;
  const int bn = blockIdx.y * 128;

  f32x4 acc[4][4];
#pragma unroll
  for (int m = 0; m < 4; m++)
#pragma unroll
    for (int n = 0; n < 4; n++) acc[m][n] = (f32x4){0.f, 0.f, 0.f, 0.f};

  for (int k0 = 0; k0 < K; k0 += 32) {
    __syncthreads();
#pragma unroll
    for (int i = 0; i < 2; i++) {
      const int sb = wv * 64 + i * 256;   // wave-uniform LDS slot base
      const int slot = sb + lane;
      const int row = slot >> 2, c8 = slot & 3;
      gload_lds16(A + (size_t)(bm + row) * K + k0 + c8 * 8, &As[sb * 8]);
      gload_lds16(Bw + (size_t)(bn + row) * K + k0 + c8 * 8, &Bs[sb * 8]);
    }
    __syncthreads();

    short8 af[4], bfr[4];
#pragma unroll
    for (int m = 0; m < 4; m++)
      af[m] = *(const short8*)&As[(wr * 64 + m * 16 + lrow) * 32 + lgrp * 8];
#pragma unroll
    for (int n = 0; n < 4; n++)
      bfr[n] = *(const short8*)&Bs[(wc * 64 + n * 16 + lrow) * 32 + lgrp * 8];
#pragma unroll
    for (int m = 0; m < 4; m++)
#pragma unroll
      for (int n = 0; n < 4; n++)
        acc[m][n] = __builtin_amdgcn_mfma_f32_16x16x32_bf16(af[m], bfr[n], acc[m][n], 0, 0, 0);
  }

  if constexpr (EPI == 0) {
    const int proj = bn >> 9;  // block-uniform: 0=Q, 1=K, 2=V
    if (proj == 2) {
      // --- V: transpose 128x128 tile via LDS, store [bh][d][s] coalesced ---
      __shared__ __align__(16) unsigned short VT[128 * 136];
#pragma unroll
      for (int n = 0; n < 4; n++) {
        const int cl = wc * 64 + n * 16 + lrow;  // local col (d-direction)
        const float bval = bias[bn + cl];
#pragma unroll
        for (int m = 0; m < 4; m++)
#pragma unroll
          for (int r = 0; r < 4; r++)
            VT[cl * 136 + wr * 64 + m * 16 + lgrp * 4 + r] = f2bf(acc[m][n][r] + bval);
      }
      __syncthreads();
      const int j = (bn - 1024) >> 7;   // 0..3
      const int b = bm >> 11;
      const int sbase = bm & 2047;
      unsigned short* vout = outb + (size_t)2 * 4194304;
#pragma unroll
      for (int q = 0; q < 8; q++) {
        const int chunk = q * 256 + tid;       // 2048 chunks of 8 elems
        const int cl = chunk >> 4, s8 = chunk & 15;
        const int head = 2 * j + (cl >> 6), d = cl & 63;
        ushort8 val = *(const ushort8*)&VT[cl * 136 + s8 * 8];
        *(ushort8*)(vout + ((size_t)(b * 8 + head) * 64 + d) * 2048 + sbase + s8 * 8) = val;
      }
    } else {
      const float qs = (proj == 0) ? 0.18033688011f : 1.0f;  // log2(e)/8
#pragma unroll
      for (int m = 0; m < 4; m++) {
#pragma unroll
        for (int n = 0; n < 4; n++) {
          const int gcol = bn + wc * 64 + n * 16 + lrow;
          const float bval = bias[gcol];
          const int feat = gcol & 511;
          const int head = feat >> 6, d = feat & 63;
#pragma unroll
          for (int r = 0; r < 4; r++) {
            const int grow = bm + wr * 64 + m * 16 + lgrp * 4 + r;
            const int b = grow >> 11, s = grow & 2047;
            const int bh = b * 8 + head;
            outb[(size_t)proj * 4194304 + ((size_t)bh * 2048 + s) * 64 + d] =
                f2bf((acc[m][n][r] + bval) * qs);
          }
        }
      }
    }
  } else {
#pragma unroll
    for (int m = 0; m < 4; m++) {
#pragma unroll
      for (int n = 0; n < 4; n++) {
        const int gcol = bn + wc * 64 + n * 16 + lrow;
        const float bval = bias[gcol];
#pragma unroll
        for (int r = 0; r < 4; r++) {
          const int grow = bm + wr * 64 + m * 16 + lgrp * 4 + r;
          float v = acc[m][n][r] + bval;
          const size_t o = (size_t)grow * N + gcol;
          if constexpr (EPI == 1) {
            outb[o] = f2bf(v + bf2f(residb[o]));
          } else if constexpr (EPI == 2) {
            outb[o] = f2bf(v > 0.f ? v : 0.f);
          } else {
            outf[o] = v + bf2f(residb[o]);
          }
        }
      }
    }
  }
}

// ---------------------------------------------------------------------------
// GEMM 128x64 tile (BK=32, 4 waves, each wave owns 32 rows x 64 cols).
// For narrow-N GEMMs (N=512): grid = (M/128) x (N/64) = 512 blocks -> 2/CU.
// EPI 1: bf16 out + bf16 residual; EPI 3: fp32 out + bf16 residual.
// ---------------------------------------------------------------------------
template <int EPI>
__global__ __launch_bounds__(256) void gemm_n64(
    const unsigned short* __restrict__ A, const unsigned short* __restrict__ Bw,
    const float* __restrict__ bias, int M, int N, int K,
    unsigned short* __restrict__ outb, float* __restrict__ outf,
    const unsigned short* __restrict__ residb) {
  __shared__ __align__(16) unsigned short As[128 * 32];
  __shared__ __align__(16) unsigned short Bs[64 * 32];
  const int tid = threadIdx.x;
  const int lane = tid & 63;
  const int wv = tid >> 6;
  const int lrow = lane & 15, lgrp = lane >> 4;
  const int bm = blockIdx.x * 128;
  const int bn = blockIdx.y * 64;

  f32x4 acc[2][4];
#pragma unroll
  for (int m = 0; m < 2; m++)
#pragma unroll
    for (int n = 0; n < 4; n++) acc[m][n] = (f32x4){0.f, 0.f, 0.f, 0.f};

  for (int k0 = 0; k0 < K; k0 += 32) {
    __syncthreads();
    // A tile: 512 chunks (2 iters); B tile: 256 chunks (1 iter)
#pragma unroll
    for (int i = 0; i < 2; i++) {
      const int sb = wv * 64 + i * 256;
      const int slot = sb + lane;
      const int row = slot >> 2, c8 = slot & 3;
      gload_lds16(A + (size_t)(bm + row) * K + k0 + c8 * 8, &As[sb * 8]);
    }
    {
      const int sb = wv * 64;
      const int slot = sb + lane;
      const int row = slot >> 2, c8 = slot & 3;
      gload_lds16(Bw + (size_t)(bn + row) * K + k0 + c8 * 8, &Bs[sb * 8]);
    }
    __syncthreads();

    short8 af[2], bfr[4];
#pragma unroll
    for (int m = 0; m < 2; m++)
      af[m] = *(const short8*)&As[(wv * 32 + m * 16 + lrow) * 32 + lgrp * 8];
#pragma unroll
    for (int n = 0; n < 4; n++)
      bfr[n] = *(const short8*)&Bs[(n * 16 + lrow) * 32 + lgrp * 8];
#pragma unroll
    for (int m = 0; m < 2; m++)
#pragma unroll
      for (int n = 0; n < 4; n++)
        acc[m][n] = __builtin_amdgcn_mfma_f32_16x16x32_bf16(af[m], bfr[n], acc[m][n], 0, 0, 0);
  }

#pragma unroll
  for (int m = 0; m < 2; m++) {
#pragma unroll
    for (int n = 0; n < 4; n++) {
      const int gcol = bn + n * 16 + lrow;
      const float bval = bias[gcol];
#pragma unroll
      for (int r = 0; r < 4; r++) {
        const int grow = bm + wv * 32 + m * 16 + lgrp * 4 + r;
        float v = acc[m][n][r] + bval;
        const size_t o = (size_t)grow * N + gcol;
        if constexpr (EPI == 1) {
          outb[o] = f2bf(v + bf2f(residb[o]));
        } else {
          outf[o] = v + bf2f(residb[o]);
        }
      }
    }
  }
}

// ---------------------------------------------------------------------------
// Flash attention: no-max softmax; single-buffer K/V staged via
// global_load_lds with XOR chunk swizzle; 2 q-tiles (128 q rows) per block
// so each K/V stage serves 2x compute. 512 blocks, XCD-chunked.
// Q,K in [B*NH][2048][64] bf16 (Q pre-scaled by log2e/8); V pre-transposed
// [B*NH][64][2048] bf16. Output [B*2048][512] bf16.
// ---------------------------------------------------------------------------
__global__ __launch_bounds__(256) void attn_k(
    const unsigned short* __restrict__ Qg, const unsigned short* __restrict__ Kg,
    const unsigned short* __restrict__ Vg, unsigned short* __restrict__ Og) {
  __shared__ __align__(16) unsigned short Kl[64 * 64];
  __shared__ __align__(16) unsigned short Vl[64 * 64];
  __shared__ __align__(16) unsigned short Pl[4][16 * 88];
  const int tid = threadIdx.x, lane = tid & 63, wq = tid >> 6;
  const int lrow = lane & 15, lgrp = lane >> 4;
  // XCD-chunked swizzle: 512 blocks, 8 XCDs -> 64 consecutive per XCD
  const int bid = blockIdx.x;
  const int lin = (bid & 7) * 64 + (bid >> 3);
  const int bh = lin >> 4;          // head (4 consecutive heads per XCD)
  const int q0 = (lin & 15) * 128;  // 128-row q-slab
  const size_t hbase = (size_t)bh * (2048 * 64);

  short8 qf[2][2];
#pragma unroll
  for (int t = 0; t < 2; t++) {
    const unsigned short* qp =
        Qg + hbase + (size_t)(q0 + t * 64 + wq * 16 + lrow) * 64 + lgrp * 8;
    qf[t][0] = *(const short8*)qp;
    qf[t][1] = *(const short8*)(qp + 32);
  }

  f32x4 oacc0[4], oacc1[4];
#pragma unroll
  for (int f = 0; f < 4; f++) {
    oacc0[f] = (f32x4){0.f, 0.f, 0.f, 0.f};
    oacc1[f] = (f32x4){0.f, 0.f, 0.f, 0.f};
  }
  float lr0[4] = {0.f, 0.f, 0.f, 0.f};
  float lr1[4] = {0.f, 0.f, 0.f, 0.f};

  for (int kt = 0; kt < 2048; kt += 64) {
    __syncthreads();
#pragma unroll
    for (int i = 0; i < 2; i++) {
      const int sb = wq * 64 + i * 256;   // wave-uniform LDS slot base
      const int slot = sb + lane;
      const int r = slot >> 3;
      const int c = (slot & 7) ^ (r & 7);
      gload_lds16(Kg + hbase + (size_t)(kt + r) * 64 + c * 8, &Kl[sb * 8]);
      gload_lds16(Vg + hbase + (size_t)r * 2048 + kt + c * 8, &Vl[sb * 8]);
    }
    __syncthreads();

#pragma unroll
    for (int t = 0; t < 2; t++) {
      f32x4* oacc = t ? oacc1 : oacc0;
      float* lr = t ? lr1 : lr0;
      f32x4 sc[4];
#pragma unroll
      for (int f = 0; f < 4; f++) sc[f] = (f32x4){0.f, 0.f, 0.f, 0.f};
      __builtin_amdgcn_s_setprio(1);
#pragma unroll
      for (int f = 0; f < 4; f++) {
        const int r = f * 16 + lrow;
        short8 k0f = *(const short8*)&Kl[(r * 8 + (lgrp ^ (r & 7))) * 8];
        short8 k1f = *(const short8*)&Kl[(r * 8 + ((4 | lgrp) ^ (r & 7))) * 8];
        sc[f] = __builtin_amdgcn_mfma_f32_16x16x32_bf16(qf[t][0], k0f, sc[f], 0, 0, 0);
        sc[f] = __builtin_amdgcn_mfma_f32_16x16x32_bf16(qf[t][1], k1f, sc[f], 0, 0, 0);
      }
      __builtin_amdgcn_s_setprio(0);

      // p = 2^s (Q carries the 1/8*log2e scale); lane-local sum; pack pairs.
#pragma unroll
      for (int fp = 0; fp < 4; fp += 2) {
#pragma unroll
        for (int r = 0; r < 4; r++) {
          const float p0 = __builtin_amdgcn_exp2f(sc[fp][r]);
          const float p1 = __builtin_amdgcn_exp2f(sc[fp + 1][r]);
          lr[r] += p0 + p1;
          unsigned u;
          asm("v_cvt_pk_bf16_f32 %0, %1, %2" : "=v"(u) : "v"(p0), "v"(p1));
          Pl[wq][(lgrp * 4 + r) * 88 + lrow + 16 * fp] = (unsigned short)(u & 0xffffu);
          Pl[wq][(lgrp * 4 + r) * 88 + lrow + 16 * (fp + 1)] = (unsigned short)(u >> 16);
        }
      }

      short8 pa0 = *(const short8*)&Pl[wq][lrow * 88 + lgrp * 8];
      short8 pa1 = *(const short8*)&Pl[wq][lrow * 88 + 32 + lgrp * 8];
      __builtin_amdgcn_s_setprio(1);
#pragma unroll
      for (int f = 0; f < 4; f++) {
        const int r = f * 16 + lrow;
        short8 vb0 = *(const short8*)&Vl[(r * 8 + (lgrp ^ (r & 7))) * 8];
        short8 vb1 = *(const short8*)&Vl[(r * 8 + ((4 | lgrp) ^ (r & 7))) * 8];
        oacc[f] = __builtin_amdgcn_mfma_f32_16x16x32_bf16(pa0, vb0, oacc[f], 0, 0, 0);
        oacc[f] = __builtin_amdgcn_mfma_f32_16x16x32_bf16(pa1, vb1, oacc[f], 0, 0, 0);
      }
      __builtin_amdgcn_s_setprio(0);
    }
  }

  const int b = bh >> 3, h = bh & 7;
#pragma unroll
  for (int t = 0; t < 2; t++) {
    f32x4* oacc = t ? oacc1 : oacc0;
    float* lr = t ? lr1 : lr0;
    float inv[4];
#pragma unroll
    for (int r = 0; r < 4; r++) {
      float s = lr[r];
#pragma unroll
      for (int off = 8; off >= 1; off >>= 1) s += __shfl_xor(s, off);
      inv[r] = 1.0f / s;
    }
#pragma unroll
    for (int f = 0; f < 4; f++) {
#pragma unroll
      for (int r = 0; r < 4; r++) {
        const int row = q0 + t * 64 + wq * 16 + lgrp * 4 + r;
        Og[((size_t)(b * 2048 + row)) * 512 + h * 64 + f * 16 + lrow] =
            f2bf(oacc[f][r] * inv[r]);
      }
    }
  }
}

// ---------------------------------------------------------------------------
// LayerNorm over last dim (512), one wave per token.
// ---------------------------------------------------------------------------
__global__ __launch_bounds__(64) void ln_k(const float* __restrict__ in,
                                           const float* __restrict__ g,
                                           const float* __restrict__ bb,
                                           float* __restrict__ outf) {
  const int row = blockIdx.x, lane = threadIdx.x;
  const float4* p = (const float4*)(in + (size_t)row * 512);
  float4 a = p[lane], b4 = p[lane + 64];
  float s = a.x + a.y + a.z + a.w + b4.x + b4.y + b4.z + b4.w;
#pragma unroll
  for (int off = 32; off >= 1; off >>= 1) s += __shfl_xor(s, off);
  const float mu = s * (1.f / 512.f);
  float q = 0.f;
  {
    float d;
    d = a.x - mu; q += d * d; d = a.y - mu; q += d * d;
    d = a.z - mu; q += d * d; d = a.w - mu; q += d * d;
    d = b4.x - mu; q += d * d; d = b4.y - mu; q += d * d;
    d = b4.z - mu; q += d * d; d = b4.w - mu; q += d * d;
  }
#pragma unroll
  for (int off = 32; off >= 1; off >>= 1) q += __shfl_xor(q, off);
  const float rstd = rsqrtf(q * (1.f / 512.f) + 1e-5f);
  const float4* gp = (const float4*)g;
  const float4* bp = (const float4*)bb;
  float4 g0 = gp[lane], g1 = gp[lane + 64], c0 = bp[lane], c1 = bp[lane + 64];
  float4 o0, o1;
  o0.x = (a.x - mu) * rstd * g0.x + c0.x;
  o0.y = (a.y - mu) * rstd * g0.y + c0.y;
  o0.z = (a.z - mu) * rstd * g0.z + c0.z;
  o0.w = (a.w - mu) * rstd * g0.w + c0.w;
  o1.x = (b4.x - mu) * rstd * g1.x + c1.x;
  o1.y = (b4.y - mu) * rstd * g1.y + c1.y;
  o1.z = (b4.z - mu) * rstd * g1.z + c1.z;
  o1.w = (b4.w - mu) * rstd * g1.w + c1.w;
  float4* of = (float4*)(outf + (size_t)row * 512);
  of[lane] = o0;
  of[lane + 64] = o1;
}

__global__ __launch_bounds__(64) void ln_bf_k(const unsigned short* __restrict__ in,
                                              const float* __restrict__ g,
                                              const float* __restrict__ bb,
                                              unsigned short* __restrict__ out) {
  const int row = blockIdx.x, lane = threadIdx.x;
  ushort8 v = *(const ushort8*)(in + (size_t)row * 512 + lane * 8);
  float f[8];
#pragma unroll
  for (int j = 0; j < 8; j++) f[j] = bf2f(v[j]);
  float s = 0.f;
#pragma unroll
  for (int j = 0; j < 8; j++) s += f[j];
#pragma unroll
  for (int off = 32; off >= 1; off >>= 1) s += __shfl_xor(s, off);
  const float mu = s * (1.f / 512.f);
  float q = 0.f;
#pragma unroll
  for (int j = 0; j < 8; j++) { const float d = f[j] - mu; q += d * d; }
#pragma unroll
  for (int off = 32; off >= 1; off >>= 1) q += __shfl_xor(q, off);
  const float rstd = rsqrtf(q * (1.f / 512.f) + 1e-5f);
  const float4* gp = (const float4*)g;
  const float4* bp = (const float4*)bb;
  float4 g0 = gp[lane * 2], g1 = gp[lane * 2 + 1];
  float4 c0 = bp[lane * 2], c1 = bp[lane * 2 + 1];
  const float gg[8] = {g0.x, g0.y, g0.z, g0.w, g1.x, g1.y, g1.z, g1.w};
  const float cc[8] = {c0.x, c0.y, c0.z, c0.w, c1.x, c1.y, c1.z, c1.w};
  ushort8 ov;
#pragma unroll
  for (int j = 0; j < 8; j++) ov[j] = f2bf((f[j] - mu) * rstd * gg[j] + cc[j]);
  *(ushort8*)(out + (size_t)row * 512 + lane * 8) = ov;
}

// ---------------------------------------------------------------------------
extern "C" void kernel_launch(void* const* d_in, const int* in_sizes, int n_in,
                              void* d_out, int out_size, void* d_ws, size_t ws_size,
                              hipStream_t stream) {
  const float* x = (const float*)d_in[0];
  const float* wq = (const float*)d_in[1];
  const float* bq = (const float*)d_in[2];
  const float* wk = (const float*)d_in[3];
  const float* bk = (const float*)d_in[4];
  const float* wv = (const float*)d_in[5];
  const float* bv = (const float*)d_in[6];
  const float* wo = (const float*)d_in[7];
  const float* bo = (const float*)d_in[8];
  const float* ln_g = (const float*)d_in[9];
  const float* ln_b = (const float*)d_in[10];
  const float* w1 = (const float*)d_in[11];
  const float* b1 = (const float*)d_in[12];
  const float* w2 = (const float*)d_in[13];
  const float* b2 = (const float*)d_in[14];

  // workspace carve-up (ushort elems)
  unsigned short* ws_u = (unsigned short*)d_ws;
  unsigned short* wqkv = ws_u;                   // 786432
  unsigned short* wob = wqkv + 786432;           // 262144
  unsigned short* w1b = wob + 262144;            // 1048576
  unsigned short* w2b = w1b + 1048576;           // 1048576
  unsigned short* xb = w2b + 1048576;            // 4194304  [8192][512]
  unsigned short* qb = xb + 4194304;             // [32][2048][64]
  unsigned short* kb = qb + 4194304;             // [32][2048][64]
  unsigned short* vtb = kb + 4194304;            // V^T [32][64][2048]
  unsigned short* ob = vtb + 4194304;            // attn out [8192][512]
  unsigned short* s1b = ob + 4194304;            // h_pre bf16 [8192][512]
  unsigned short* hb = s1b + 4194304;            // h bf16 [8192][512]
  unsigned short* f1b = qb;                      // reuse qb..ob: [8192][2048]
  float* bqkv = (float*)(hb + 4194304);          // 1536

  // one fused convert launch for all weights + x
  cvt_all_k<<<7168, 256, 0, stream>>>(
      (const float4*)wq, (const float4*)wk, (const float4*)wv, (const float4*)wo,
      (const float4*)w1, (const float4*)w2, (const float4*)x,
      (ushort4v*)wqkv, (ushort4v*)wob, (ushort4v*)w1b, (ushort4v*)w2b,
      (ushort4v*)xb);
  pack_bias_k<<<1, 512, 0, stream>>>(bq, bk, bv, bqkv);

  // QKV projection: M=8192, N=1536, K=512 -> scatter into qb/kb/vtb
  gemm_bt<0><<<dim3(64, 12), 256, 0, stream>>>(xb, wqkv, bqkv, 8192, 1536, 512,
                                               qb, nullptr, nullptr);
  // attention (512 blocks, XCD-chunked internally)
  attn_k<<<512, 256, 0, stream>>>(qb, kb, vtb, ob);
  // O projection + residual(xb): -> s1b bf16   (128x64 tiles -> 512 blocks)
  gemm_n64<1><<<dim3(64, 8), 256, 0, stream>>>(ob, wob, bo, 8192, 512, 512,
                                               s1b, nullptr, xb);
  // LN1 (bf16 -> bf16)
  ln_bf_k<<<8192, 64, 0, stream>>>(s1b, ln_g, ln_b, hb);
  // FFN1 + ReLU: M=8192, N=2048, K=512 -> f1b bf16
  gemm_bt<2><<<dim3(64, 16), 256, 0, stream>>>(hb, w1b, b1, 8192, 2048, 512,
                                               f1b, nullptr, nullptr);
  // FFN2 + residual(hb): M=8192, N=512, K=2048 -> d_out fp32 (128x64 tiles)
  gemm_n64<3><<<dim3(64, 8), 256, 0, stream>>>(f1b, w2b, b2, 8192, 512, 2048,
                                               nullptr, (float*)d_out, hb);
  // LN2 in-place on d_out
  ln_k<<<8192, 64, 0, stream>>>((float*)d_out, ln_g, ln_b, (float*)d_out);
}

// Round 8
// 178.014 us; speedup vs baseline: 1.3207x; 1.1047x over previous
//
#include <hip/hip_runtime.h>

typedef __attribute__((ext_vector_type(8))) short short8;
typedef __attribute__((ext_vector_type(8))) unsigned short ushort8;
typedef __attribute__((ext_vector_type(4))) unsigned short ushort4v;
typedef __attribute__((ext_vector_type(4))) float f32x4;

#define DEV static __device__ __forceinline__

DEV unsigned short f2bf(float f) {
  unsigned u = __builtin_bit_cast(unsigned, f);
  u += 0x7fffu + ((u >> 16) & 1u);
  return (unsigned short)(u >> 16);
}

DEV float bf2f(unsigned short u) {
  return __builtin_bit_cast(float, (unsigned)u << 16);
}

DEV void gload_lds16(const void* g, void* l) {
  __builtin_amdgcn_global_load_lds((__attribute__((address_space(1))) void*)g,
                                   (__attribute__((address_space(3))) void*)l,
                                   16, 0, 0);
}

// ---------------------------------------------------------------------------
// fused fp32 -> bf16 convert for all 7 regions in ONE launch.
// ---------------------------------------------------------------------------
__global__ __launch_bounds__(256) void cvt_all_k(
    const float4* __restrict__ wq, const float4* __restrict__ wk,
    const float4* __restrict__ wv, const float4* __restrict__ wo,
    const float4* __restrict__ w1, const float4* __restrict__ w2,
    const float4* __restrict__ x, ushort4v* __restrict__ wqkv,
    ushort4v* __restrict__ wob, ushort4v* __restrict__ w1b,
    ushort4v* __restrict__ w2b, ushort4v* __restrict__ xb) {
  const int i = threadIdx.x;
  const int b = blockIdx.x;
  const float4* s;
  ushort4v* d;
  size_t u;
  if (b < 256)       { s = wq; d = wqkv;          u = (size_t)b * 256 + i; }
  else if (b < 512)  { s = wk; d = wqkv + 65536;  u = (size_t)(b - 256) * 256 + i; }
  else if (b < 768)  { s = wv; d = wqkv + 131072; u = (size_t)(b - 512) * 256 + i; }
  else if (b < 1024) { s = wo; d = wob;           u = (size_t)(b - 768) * 256 + i; }
  else if (b < 2048) { s = w1; d = w1b;           u = (size_t)(b - 1024) * 256 + i; }
  else if (b < 3072) { s = w2; d = w2b;           u = (size_t)(b - 2048) * 256 + i; }
  else               { s = x;  d = xb;            u = (size_t)(b - 3072) * 256 + i; }
  float4 v = s[u];
  ushort4v o = { f2bf(v.x), f2bf(v.y), f2bf(v.z), f2bf(v.w) };
  d[u] = o;
}

__global__ void pack_bias_k(const float* __restrict__ bq, const float* __restrict__ bk,
                            const float* __restrict__ bv, float* __restrict__ o) {
  int i = threadIdx.x;  // 512 threads
  o[i] = bq[i];
  o[512 + i] = bk[i];
  o[1024 + i] = bv[i];
}

// ---------------------------------------------------------------------------
// GEMM 128x128, BK=64, 4 waves. Source-pre-swizzled staging (chunk col
// c ^= row&7 on the GLOBAL side, linear LDS dest, same XOR on ds_read) so
// fragment reads are ~2-way instead of 8-way bank conflicts.
// EPI 0: QKV scatter. Q (scaled by log2e/8) -> [bh][s][d], K -> [bh][s][d],
//        V -> TRANSPOSED [bh][d][s] via LDS-transpose (coalesced stores).
// EPI 2: ReLU -> bf16 (outb)
// ---------------------------------------------------------------------------
template <int EPI>
__global__ __launch_bounds__(256) void gemm_bt(
    const unsigned short* __restrict__ A, const unsigned short* __restrict__ Bw,
    const float* __restrict__ bias, int M, int N, int K,
    unsigned short* __restrict__ outb, float* __restrict__ outf,
    const unsigned short* __restrict__ residb) {
  __shared__ __align__(16) unsigned short As[128 * 64];
  __shared__ __align__(16) unsigned short Bs[128 * 64];
  const int tid = threadIdx.x;
  const int lane = tid & 63;
  const int wv = tid >> 6;
  const int wr = wv >> 1, wc = wv & 1;
  const int lrow = lane & 15, lgrp = lane >> 4;
  const int bm = blockIdx.x * 128;
  const int bn = blockIdx.y * 128;

  f32x4 acc[4][4];
#pragma unroll
  for (int m = 0; m < 4; m++)
#pragma unroll
    for (int n = 0; n < 4; n++) acc[m][n] = (f32x4){0.f, 0.f, 0.f, 0.f};

  for (int k0 = 0; k0 < K; k0 += 64) {
    __syncthreads();
#pragma unroll
    for (int i = 0; i < 4; i++) {
      const int sb = wv * 64 + i * 256;   // wave-uniform LDS slot base
      const int slot = sb + lane;
      const int row = slot >> 3;
      const int cc = (slot & 7) ^ (row & 7);   // pre-swizzled source chunk
      gload_lds16(A + (size_t)(bm + row) * K + k0 + cc * 8, &As[sb * 8]);
      gload_lds16(Bw + (size_t)(bn + row) * K + k0 + cc * 8, &Bs[sb * 8]);
    }
    __syncthreads();

#pragma unroll
    for (int kk = 0; kk < 2; kk++) {
      short8 af[4], bfr[4];
#pragma unroll
      for (int m = 0; m < 4; m++) {
        const int row = wr * 64 + m * 16 + lrow;
        af[m] = *(const short8*)&As[row * 64 + (((lgrp + 4 * kk) ^ (row & 7)) * 8)];
      }
#pragma unroll
      for (int n = 0; n < 4; n++) {
        const int row = wc * 64 + n * 16 + lrow;
        bfr[n] = *(const short8*)&Bs[row * 64 + (((lgrp + 4 * kk) ^ (row & 7)) * 8)];
      }
#pragma unroll
      for (int m = 0; m < 4; m++)
#pragma unroll
        for (int n = 0; n < 4; n++)
          acc[m][n] = __builtin_amdgcn_mfma_f32_16x16x32_bf16(af[m], bfr[n], acc[m][n], 0, 0, 0);
    }
  }

  if constexpr (EPI == 0) {
    const int proj = bn >> 9;  // block-uniform: 0=Q, 1=K, 2=V
    if (proj == 2) {
      // --- V: transpose 128x128 tile via LDS, store [bh][d][s] coalesced ---
      __shared__ __align__(16) unsigned short VT[128 * 136];
#pragma unroll
      for (int n = 0; n < 4; n++) {
        const int cl = wc * 64 + n * 16 + lrow;  // local col (d-direction)
        const float bval = bias[bn + cl];
#pragma unroll
        for (int m = 0; m < 4; m++)
#pragma unroll
          for (int r = 0; r < 4; r++)
            VT[cl * 136 + wr * 64 + m * 16 + lgrp * 4 + r] = f2bf(acc[m][n][r] + bval);
      }
      __syncthreads();
      const int j = (bn - 1024) >> 7;   // 0..3
      const int b = bm >> 11;
      const int sbase = bm & 2047;
      unsigned short* vout = outb + (size_t)2 * 4194304;
#pragma unroll
      for (int q = 0; q < 8; q++) {
        const int chunk = q * 256 + tid;       // 2048 chunks of 8 elems
        const int cl = chunk >> 4, s8 = chunk & 15;
        const int head = 2 * j + (cl >> 6), d = cl & 63;
        ushort8 val = *(const ushort8*)&VT[cl * 136 + s8 * 8];
        *(ushort8*)(vout + ((size_t)(b * 8 + head) * 64 + d) * 2048 + sbase + s8 * 8) = val;
      }
    } else {
      const float qs = (proj == 0) ? 0.18033688011f : 1.0f;  // log2(e)/8
#pragma unroll
      for (int m = 0; m < 4; m++) {
#pragma unroll
        for (int n = 0; n < 4; n++) {
          const int gcol = bn + wc * 64 + n * 16 + lrow;
          const float bval = bias[gcol];
          const int feat = gcol & 511;
          const int head = feat >> 6, d = feat & 63;
#pragma unroll
          for (int r = 0; r < 4; r++) {
            const int grow = bm + wr * 64 + m * 16 + lgrp * 4 + r;
            const int b = grow >> 11, s = grow & 2047;
            const int bh = b * 8 + head;
            outb[(size_t)proj * 4194304 + ((size_t)bh * 2048 + s) * 64 + d] =
                f2bf((acc[m][n][r] + bval) * qs);
          }
        }
      }
    }
  } else {
#pragma unroll
    for (int m = 0; m < 4; m++) {
#pragma unroll
      for (int n = 0; n < 4; n++) {
        const int gcol = bn + wc * 64 + n * 16 + lrow;
        const float bval = bias[gcol];
#pragma unroll
        for (int r = 0; r < 4; r++) {
          const int grow = bm + wr * 64 + m * 16 + lgrp * 4 + r;
          float v = acc[m][n][r] + bval;
          const size_t o = (size_t)grow * N + gcol;
          if constexpr (EPI == 1) {
            outb[o] = f2bf(v + bf2f(residb[o]));
          } else if constexpr (EPI == 2) {
            outb[o] = f2bf(v > 0.f ? v : 0.f);
          } else {
            outf[o] = v + bf2f(residb[o]);
          }
        }
      }
    }
  }
}

// ---------------------------------------------------------------------------
// GEMM 128x64 tile, BK=64, 4 waves (each wave 32 rows x 64 cols).
// Same source-pre-swizzle staging. For narrow-N GEMMs (N=512) -> 512 blocks.
// EPI 1: bf16 out + bf16 residual; EPI 3: fp32 out + bf16 residual.
// ---------------------------------------------------------------------------
template <int EPI>
__global__ __launch_bounds__(256) void gemm_n64(
    const unsigned short* __restrict__ A, const unsigned short* __restrict__ Bw,
    const float* __restrict__ bias, int M, int N, int K,
    unsigned short* __restrict__ outb, float* __restrict__ outf,
    const unsigned short* __restrict__ residb) {
  __shared__ __align__(16) unsigned short As[128 * 64];
  __shared__ __align__(16) unsigned short Bs[64 * 64];
  const int tid = threadIdx.x;
  const int lane = tid & 63;
  const int wv = tid >> 6;
  const int lrow = lane & 15, lgrp = lane >> 4;
  const int bm = blockIdx.x * 128;
  const int bn = blockIdx.y * 64;

  f32x4 acc[2][4];
#pragma unroll
  for (int m = 0; m < 2; m++)
#pragma unroll
    for (int n = 0; n < 4; n++) acc[m][n] = (f32x4){0.f, 0.f, 0.f, 0.f};

  for (int k0 = 0; k0 < K; k0 += 64) {
    __syncthreads();
#pragma unroll
    for (int i = 0; i < 4; i++) {
      const int sb = wv * 64 + i * 256;
      const int slot = sb + lane;
      const int row = slot >> 3;
      const int cc = (slot & 7) ^ (row & 7);
      gload_lds16(A + (size_t)(bm + row) * K + k0 + cc * 8, &As[sb * 8]);
    }
#pragma unroll
    for (int i = 0; i < 2; i++) {
      const int sb = wv * 64 + i * 256;
      const int slot = sb + lane;
      const int row = slot >> 3;
      const int cc = (slot & 7) ^ (row & 7);
      gload_lds16(Bw + (size_t)(bn + row) * K + k0 + cc * 8, &Bs[sb * 8]);
    }
    __syncthreads();

#pragma unroll
    for (int kk = 0; kk < 2; kk++) {
      short8 af[2], bfr[4];
#pragma unroll
      for (int m = 0; m < 2; m++) {
        const int row = wv * 32 + m * 16 + lrow;
        af[m] = *(const short8*)&As[row * 64 + (((lgrp + 4 * kk) ^ (row & 7)) * 8)];
      }
#pragma unroll
      for (int n = 0; n < 4; n++) {
        const int row = n * 16 + lrow;
        bfr[n] = *(const short8*)&Bs[row * 64 + (((lgrp + 4 * kk) ^ (row & 7)) * 8)];
      }
#pragma unroll
      for (int m = 0; m < 2; m++)
#pragma unroll
        for (int n = 0; n < 4; n++)
          acc[m][n] = __builtin_amdgcn_mfma_f32_16x16x32_bf16(af[m], bfr[n], acc[m][n], 0, 0, 0);
    }
  }

#pragma unroll
  for (int m = 0; m < 2; m++) {
#pragma unroll
    for (int n = 0; n < 4; n++) {
      const int gcol = bn + n * 16 + lrow;
      const float bval = bias[gcol];
#pragma unroll
      for (int r = 0; r < 4; r++) {
        const int grow = bm + wv * 32 + m * 16 + lgrp * 4 + r;
        float v = acc[m][n][r] + bval;
        const size_t o = (size_t)grow * N + gcol;
        if constexpr (EPI == 1) {
          outb[o] = f2bf(v + bf2f(residb[o]));
        } else {
          outf[o] = v + bf2f(residb[o]);
        }
      }
    }
  }
}

// ---------------------------------------------------------------------------
// Flash attention: no-max softmax; single-buffer K/V staged via
// global_load_lds with XOR chunk swizzle; 2 q-tiles (128 q rows) per block.
// 512 blocks, XCD-chunked. Q,K in [B*NH][2048][64] bf16 (Q pre-scaled by
// log2e/8); V pre-transposed [B*NH][64][2048] bf16. Out [B*2048][512] bf16.
// ---------------------------------------------------------------------------
__global__ __launch_bounds__(256) void attn_k(
    const unsigned short* __restrict__ Qg, const unsigned short* __restrict__ Kg,
    const unsigned short* __restrict__ Vg, unsigned short* __restrict__ Og) {
  __shared__ __align__(16) unsigned short Kl[64 * 64];
  __shared__ __align__(16) unsigned short Vl[64 * 64];
  __shared__ __align__(16) unsigned short Pl[4][16 * 88];
  const int tid = threadIdx.x, lane = tid & 63, wq = tid >> 6;
  const int lrow = lane & 15, lgrp = lane >> 4;
  const int bid = blockIdx.x;
  const int lin = (bid & 7) * 64 + (bid >> 3);
  const int bh = lin >> 4;          // head (4 consecutive heads per XCD)
  const int q0 = (lin & 15) * 128;  // 128-row q-slab
  const size_t hbase = (size_t)bh * (2048 * 64);

  short8 qf[2][2];
#pragma unroll
  for (int t = 0; t < 2; t++) {
    const unsigned short* qp =
        Qg + hbase + (size_t)(q0 + t * 64 + wq * 16 + lrow) * 64 + lgrp * 8;
    qf[t][0] = *(const short8*)qp;
    qf[t][1] = *(const short8*)(qp + 32);
  }

  f32x4 oacc0[4], oacc1[4];
#pragma unroll
  for (int f = 0; f < 4; f++) {
    oacc0[f] = (f32x4){0.f, 0.f, 0.f, 0.f};
    oacc1[f] = (f32x4){0.f, 0.f, 0.f, 0.f};
  }
  float lr0[4] = {0.f, 0.f, 0.f, 0.f};
  float lr1[4] = {0.f, 0.f, 0.f, 0.f};

  for (int kt = 0; kt < 2048; kt += 64) {
    __syncthreads();
#pragma unroll
    for (int i = 0; i < 2; i++) {
      const int sb = wq * 64 + i * 256;   // wave-uniform LDS slot base
      const int slot = sb + lane;
      const int r = slot >> 3;
      const int c = (slot & 7) ^ (r & 7);
      gload_lds16(Kg + hbase + (size_t)(kt + r) * 64 + c * 8, &Kl[sb * 8]);
      gload_lds16(Vg + hbase + (size_t)r * 2048 + kt + c * 8, &Vl[sb * 8]);
    }
    __syncthreads();

#pragma unroll
    for (int t = 0; t < 2; t++) {
      f32x4* oacc = t ? oacc1 : oacc0;
      float* lr = t ? lr1 : lr0;
      f32x4 sc[4];
#pragma unroll
      for (int f = 0; f < 4; f++) sc[f] = (f32x4){0.f, 0.f, 0.f, 0.f};
      __builtin_amdgcn_s_setprio(1);
#pragma unroll
      for (int f = 0; f < 4; f++) {
        const int r = f * 16 + lrow;
        short8 k0f = *(const short8*)&Kl[(r * 8 + (lgrp ^ (r & 7))) * 8];
        short8 k1f = *(const short8*)&Kl[(r * 8 + ((4 | lgrp) ^ (r & 7))) * 8];
        sc[f] = __builtin_amdgcn_mfma_f32_16x16x32_bf16(qf[t][0], k0f, sc[f], 0, 0, 0);
        sc[f] = __builtin_amdgcn_mfma_f32_16x16x32_bf16(qf[t][1], k1f, sc[f], 0, 0, 0);
      }
      __builtin_amdgcn_s_setprio(0);

#pragma unroll
      for (int fp = 0; fp < 4; fp += 2) {
#pragma unroll
        for (int r = 0; r < 4; r++) {
          const float p0 = __builtin_amdgcn_exp2f(sc[fp][r]);
          const float p1 = __builtin_amdgcn_exp2f(sc[fp + 1][r]);
          lr[r] += p0 + p1;
          unsigned u;
          asm("v_cvt_pk_bf16_f32 %0, %1, %2" : "=v"(u) : "v"(p0), "v"(p1));
          Pl[wq][(lgrp * 4 + r) * 88 + lrow + 16 * fp] = (unsigned short)(u & 0xffffu);
          Pl[wq][(lgrp * 4 + r) * 88 + lrow + 16 * (fp + 1)] = (unsigned short)(u >> 16);
        }
      }

      short8 pa0 = *(const short8*)&Pl[wq][lrow * 88 + lgrp * 8];
      short8 pa1 = *(const short8*)&Pl[wq][lrow * 88 + 32 + lgrp * 8];
      __builtin_amdgcn_s_setprio(1);
#pragma unroll
      for (int f = 0; f < 4; f++) {
        const int r = f * 16 + lrow;
        short8 vb0 = *(const short8*)&Vl[(r * 8 + (lgrp ^ (r & 7))) * 8];
        short8 vb1 = *(const short8*)&Vl[(r * 8 + ((4 | lgrp) ^ (r & 7))) * 8];
        oacc[f] = __builtin_amdgcn_mfma_f32_16x16x32_bf16(pa0, vb0, oacc[f], 0, 0, 0);
        oacc[f] = __builtin_amdgcn_mfma_f32_16x16x32_bf16(pa1, vb1, oacc[f], 0, 0, 0);
      }
      __builtin_amdgcn_s_setprio(0);
    }
  }

  const int b = bh >> 3, h = bh & 7;
#pragma unroll
  for (int t = 0; t < 2; t++) {
    f32x4* oacc = t ? oacc1 : oacc0;
    float* lr = t ? lr1 : lr0;
    float inv[4];
#pragma unroll
    for (int r = 0; r < 4; r++) {
      float s = lr[r];
#pragma unroll
      for (int off = 8; off >= 1; off >>= 1) s += __shfl_xor(s, off);
      inv[r] = 1.0f / s;
    }
#pragma unroll
    for (int f = 0; f < 4; f++) {
#pragma unroll
      for (int r = 0; r < 4; r++) {
        const int row = q0 + t * 64 + wq * 16 + lgrp * 4 + r;
        Og[((size_t)(b * 2048 + row)) * 512 + h * 64 + f * 16 + lrow] =
            f2bf(oacc[f][r] * inv[r]);
      }
    }
  }
}

// ---------------------------------------------------------------------------
// LayerNorm over last dim (512), one wave per token.
// ---------------------------------------------------------------------------
__global__ __launch_bounds__(64) void ln_k(const float* __restrict__ in,
                                           const float* __restrict__ g,
                                           const float* __restrict__ bb,
                                           float* __restrict__ outf) {
  const int row = blockIdx.x, lane = threadIdx.x;
  const float4* p = (const float4*)(in + (size_t)row * 512);
  float4 a = p[lane], b4 = p[lane + 64];
  float s = a.x + a.y + a.z + a.w + b4.x + b4.y + b4.z + b4.w;
#pragma unroll
  for (int off = 32; off >= 1; off >>= 1) s += __shfl_xor(s, off);
  const float mu = s * (1.f / 512.f);
  float q = 0.f;
  {
    float d;
    d = a.x - mu; q += d * d; d = a.y - mu; q += d * d;
    d = a.z - mu; q += d * d; d = a.w - mu; q += d * d;
    d = b4.x - mu; q += d * d; d = b4.y - mu; q += d * d;
    d = b4.z - mu; q += d * d; d = b4.w - mu; q += d * d;
  }
#pragma unroll
  for (int off = 32; off >= 1; off >>= 1) q += __shfl_xor(q, off);
  const float rstd = rsqrtf(q * (1.f / 512.f) + 1e-5f);
  const float4* gp = (const float4*)g;
  const float4* bp = (const float4*)bb;
  float4 g0 = gp[lane], g1 = gp[lane + 64], c0 = bp[lane], c1 = bp[lane + 64];
  float4 o0, o1;
  o0.x = (a.x - mu) * rstd * g0.x + c0.x;
  o0.y = (a.y - mu) * rstd * g0.y + c0.y;
  o0.z = (a.z - mu) * rstd * g0.z + c0.z;
  o0.w = (a.w - mu) * rstd * g0.w + c0.w;
  o1.x = (b4.x - mu) * rstd * g1.x + c1.x;
  o1.y = (b4.y - mu) * rstd * g1.y + c1.y;
  o1.z = (b4.z - mu) * rstd * g1.z + c1.z;
  o1.w = (b4.w - mu) * rstd * g1.w + c1.w;
  float4* of = (float4*)(outf + (size_t)row * 512);
  of[lane] = o0;
  of[lane + 64] = o1;
}

__global__ __launch_bounds__(64) void ln_bf_k(const unsigned short* __restrict__ in,
                                              const float* __restrict__ g,
                                              const float* __restrict__ bb,
                                              unsigned short* __restrict__ out) {
  const int row = blockIdx.x, lane = threadIdx.x;
  ushort8 v = *(const ushort8*)(in + (size_t)row * 512 + lane * 8);
  float f[8];
#pragma unroll
  for (int j = 0; j < 8; j++) f[j] = bf2f(v[j]);
  float s = 0.f;
#pragma unroll
  for (int j = 0; j < 8; j++) s += f[j];
#pragma unroll
  for (int off = 32; off >= 1; off >>= 1) s += __shfl_xor(s, off);
  const float mu = s * (1.f / 512.f);
  float q = 0.f;
#pragma unroll
  for (int j = 0; j < 8; j++) { const float d = f[j] - mu; q += d * d; }
#pragma unroll
  for (int off = 32; off >= 1; off >>= 1) q += __shfl_xor(q, off);
  const float rstd = rsqrtf(q * (1.f / 512.f) + 1e-5f);
  const float4* gp = (const float4*)g;
  const float4* bp = (const float4*)bb;
  float4 g0 = gp[lane * 2], g1 = gp[lane * 2 + 1];
  float4 c0 = bp[lane * 2], c1 = bp[lane * 2 + 1];
  const float gg[8] = {g0.x, g0.y, g0.z, g0.w, g1.x, g1.y, g1.z, g1.w};
  const float cc[8] = {c0.x, c0.y, c0.z, c0.w, c1.x, c1.y, c1.z, c1.w};
  ushort8 ov;
#pragma unroll
  for (int j = 0; j < 8; j++) ov[j] = f2bf((f[j] - mu) * rstd * gg[j] + cc[j]);
  *(ushort8*)(out + (size_t)row * 512 + lane * 8) = ov;
}

// ---------------------------------------------------------------------------
extern "C" void kernel_launch(void* const* d_in, const int* in_sizes, int n_in,
                              void* d_out, int out_size, void* d_ws, size_t ws_size,
                              hipStream_t stream) {
  const float* x = (const float*)d_in[0];
  const float* wq = (const float*)d_in[1];
  const float* bq = (const float*)d_in[2];
  const float* wk = (const float*)d_in[3];
  const float* bk = (const float*)d_in[4];
  const float* wv = (const float*)d_in[5];
  const float* bv = (const float*)d_in[6];
  const float* wo = (const float*)d_in[7];
  const float* bo = (const float*)d_in[8];
  const float* ln_g = (const float*)d_in[9];
  const float* ln_b = (const float*)d_in[10];
  const float* w1 = (const float*)d_in[11];
  const float* b1 = (const float*)d_in[12];
  const float* w2 = (const float*)d_in[13];
  const float* b2 = (const float*)d_in[14];

  // workspace carve-up (ushort elems)
  unsigned short* ws_u = (unsigned short*)d_ws;
  unsigned short* wqkv = ws_u;                   // 786432
  unsigned short* wob = wqkv + 786432;           // 262144
  unsigned short* w1b = wob + 262144;            // 1048576
  unsigned short* w2b = w1b + 1048576;           // 1048576
  unsigned short* xb = w2b + 1048576;            // 4194304  [8192][512]
  unsigned short* qb = xb + 4194304;             // [32][2048][64]
  unsigned short* kb = qb + 4194304;             // [32][2048][64]
  unsigned short* vtb = kb + 4194304;            // V^T [32][64][2048]
  unsigned short* ob = vtb + 4194304;            // attn out [8192][512]
  unsigned short* s1b = ob + 4194304;            // h_pre bf16 [8192][512]
  unsigned short* hb = s1b + 4194304;            // h bf16 [8192][512]
  unsigned short* f1b = qb;                      // reuse qb..ob: [8192][2048]
  float* bqkv = (float*)(hb + 4194304);          // 1536

  // one fused convert launch for all weights + x
  cvt_all_k<<<7168, 256, 0, stream>>>(
      (const float4*)wq, (const float4*)wk, (const float4*)wv, (const float4*)wo,
      (const float4*)w1, (const float4*)w2, (const float4*)x,
      (ushort4v*)wqkv, (ushort4v*)wob, (ushort4v*)w1b, (ushort4v*)w2b,
      (ushort4v*)xb);
  pack_bias_k<<<1, 512, 0, stream>>>(bq, bk, bv, bqkv);

  // QKV projection: M=8192, N=1536, K=512 -> scatter into qb/kb/vtb
  gemm_bt<0><<<dim3(64, 12), 256, 0, stream>>>(xb, wqkv, bqkv, 8192, 1536, 512,
                                               qb, nullptr, nullptr);
  // attention (512 blocks, XCD-chunked internally)
  attn_k<<<512, 256, 0, stream>>>(qb, kb, vtb, ob);
  // O projection + residual(xb): -> s1b bf16   (128x64 tiles -> 512 blocks)
  gemm_n64<1><<<dim3(64, 8), 256, 0, stream>>>(ob, wob, bo, 8192, 512, 512,
                                               s1b, nullptr, xb);
  // LN1 (bf16 -> bf16)
  ln_bf_k<<<8192, 64, 0, stream>>>(s1b, ln_g, ln_b, hb);
  // FFN1 + ReLU: M=8192, N=2048, K=512 -> f1b bf16
  gemm_bt<2><<<dim3(64, 16), 256, 0, stream>>>(hb, w1b, b1, 8192, 2048, 512,
                                               f1b, nullptr, nullptr);
  // FFN2 + residual(hb): M=8192, N=512, K=2048 -> d_out fp32 (128x64 tiles)
  gemm_n64<3><<<dim3(64, 8), 256, 0, stream>>>(f1b, w2b, b2, 8192, 512, 2048,
                                               nullptr, (float*)d_out, hb);
  // LN2 in-place on d_out
  ln_k<<<8192, 64, 0, stream>>>((float*)d_out, ln_g, ln_b, (float*)d_out);
}

// Round 9
// 171.675 us; speedup vs baseline: 1.3694x; 1.0369x over previous
//
#include <hip/hip_runtime.h>

typedef __attribute__((ext_vector_type(8))) short short8;
typedef __attribute__((ext_vector_type(8))) unsigned short ushort8;
typedef __attribute__((ext_vector_type(4))) unsigned short ushort4v;
typedef __attribute__((ext_vector_type(4))) float f32x4;
typedef __attribute__((ext_vector_type(16))) float f32x16;

#define DEV static __device__ __forceinline__

DEV unsigned short f2bf(float f) {
  unsigned u = __builtin_bit_cast(unsigned, f);
  u += 0x7fffu + ((u >> 16) & 1u);
  return (unsigned short)(u >> 16);
}

DEV float bf2f(unsigned short u) {
  return __builtin_bit_cast(float, (unsigned)u << 16);
}

DEV void gload_lds16(const void* g, void* l) {
  __builtin_amdgcn_global_load_lds((__attribute__((address_space(1))) void*)g,
                                   (__attribute__((address_space(3))) void*)l,
                                   16, 0, 0);
}

DEV unsigned cvtpk(float lo, float hi) {
  unsigned u;
  asm("v_cvt_pk_bf16_f32 %0, %1, %2" : "=v"(u) : "v"(lo), "v"(hi));
  return u;
}

DEV short8 pack4(unsigned a, unsigned b, unsigned c, unsigned d) {
  int4 t = make_int4((int)a, (int)b, (int)c, (int)d);
  return __builtin_bit_cast(short8, t);
}

// ---------------------------------------------------------------------------
// fused fp32 -> bf16 convert for all 7 regions in ONE launch.
// ---------------------------------------------------------------------------
__global__ __launch_bounds__(256) void cvt_all_k(
    const float4* __restrict__ wq, const float4* __restrict__ wk,
    const float4* __restrict__ wv, const float4* __restrict__ wo,
    const float4* __restrict__ w1, const float4* __restrict__ w2,
    const float4* __restrict__ x, ushort4v* __restrict__ wqkv,
    ushort4v* __restrict__ wob, ushort4v* __restrict__ w1b,
    ushort4v* __restrict__ w2b, ushort4v* __restrict__ xb) {
  const int i = threadIdx.x;
  const int b = blockIdx.x;
  const float4* s;
  ushort4v* d;
  size_t u;
  if (b < 256)       { s = wq; d = wqkv;          u = (size_t)b * 256 + i; }
  else if (b < 512)  { s = wk; d = wqkv + 65536;  u = (size_t)(b - 256) * 256 + i; }
  else if (b < 768)  { s = wv; d = wqkv + 131072; u = (size_t)(b - 512) * 256 + i; }
  else if (b < 1024) { s = wo; d = wob;           u = (size_t)(b - 768) * 256 + i; }
  else if (b < 2048) { s = w1; d = w1b;           u = (size_t)(b - 1024) * 256 + i; }
  else if (b < 3072) { s = w2; d = w2b;           u = (size_t)(b - 2048) * 256 + i; }
  else               { s = x;  d = xb;            u = (size_t)(b - 3072) * 256 + i; }
  float4 v = s[u];
  ushort4v o = { f2bf(v.x), f2bf(v.y), f2bf(v.z), f2bf(v.w) };
  d[u] = o;
}

__global__ void pack_bias_k(const float* __restrict__ bq, const float* __restrict__ bk,
                            const float* __restrict__ bv, float* __restrict__ o) {
  int i = threadIdx.x;  // 512 threads
  o[i] = bq[i];
  o[512 + i] = bk[i];
  o[1024 + i] = bv[i];
}

// ---------------------------------------------------------------------------
// GEMM 128x128, BK=64, 4 waves. Source-pre-swizzled staging.
// EPI 0: QKV scatter. Q (scaled by log2e/8) -> [bh][s][d], K -> [bh][s][d],
//        V -> TRANSPOSED [bh][d][s] via LDS-transpose (coalesced stores).
// EPI 2: ReLU -> bf16 (outb)
// ---------------------------------------------------------------------------
template <int EPI>
__global__ __launch_bounds__(256) void gemm_bt(
    const unsigned short* __restrict__ A, const unsigned short* __restrict__ Bw,
    const float* __restrict__ bias, int M, int N, int K,
    unsigned short* __restrict__ outb, float* __restrict__ outf,
    const unsigned short* __restrict__ residb) {
  __shared__ __align__(16) unsigned short As[128 * 64];
  __shared__ __align__(16) unsigned short Bs[128 * 64];
  const int tid = threadIdx.x;
  const int lane = tid & 63;
  const int wv = tid >> 6;
  const int wr = wv >> 1, wc = wv & 1;
  const int lrow = lane & 15, lgrp = lane >> 4;
  const int bm = blockIdx.x * 128;
  const int bn = blockIdx.y * 128;

  f32x4 acc[4][4];
#pragma unroll
  for (int m = 0; m < 4; m++)
#pragma unroll
    for (int n = 0; n < 4; n++) acc[m][n] = (f32x4){0.f, 0.f, 0.f, 0.f};

  for (int k0 = 0; k0 < K; k0 += 64) {
    __syncthreads();
#pragma unroll
    for (int i = 0; i < 4; i++) {
      const int sb = wv * 64 + i * 256;   // wave-uniform LDS slot base
      const int slot = sb + lane;
      const int row = slot >> 3;
      const int cc = (slot & 7) ^ (row & 7);   // pre-swizzled source chunk
      gload_lds16(A + (size_t)(bm + row) * K + k0 + cc * 8, &As[sb * 8]);
      gload_lds16(Bw + (size_t)(bn + row) * K + k0 + cc * 8, &Bs[sb * 8]);
    }
    __syncthreads();

#pragma unroll
    for (int kk = 0; kk < 2; kk++) {
      short8 af[4], bfr[4];
#pragma unroll
      for (int m = 0; m < 4; m++) {
        const int row = wr * 64 + m * 16 + lrow;
        af[m] = *(const short8*)&As[row * 64 + (((lgrp + 4 * kk) ^ (row & 7)) * 8)];
      }
#pragma unroll
      for (int n = 0; n < 4; n++) {
        const int row = wc * 64 + n * 16 + lrow;
        bfr[n] = *(const short8*)&Bs[row * 64 + (((lgrp + 4 * kk) ^ (row & 7)) * 8)];
      }
#pragma unroll
      for (int m = 0; m < 4; m++)
#pragma unroll
        for (int n = 0; n < 4; n++)
          acc[m][n] = __builtin_amdgcn_mfma_f32_16x16x32_bf16(af[m], bfr[n], acc[m][n], 0, 0, 0);
    }
  }

  if constexpr (EPI == 0) {
    const int proj = bn >> 9;  // block-uniform: 0=Q, 1=K, 2=V
    if (proj == 2) {
      // --- V: transpose 128x128 tile via LDS, store [bh][d][s] coalesced ---
      __shared__ __align__(16) unsigned short VT[128 * 136];
#pragma unroll
      for (int n = 0; n < 4; n++) {
        const int cl = wc * 64 + n * 16 + lrow;  // local col (d-direction)
        const float bval = bias[bn + cl];
#pragma unroll
        for (int m = 0; m < 4; m++)
#pragma unroll
          for (int r = 0; r < 4; r++)
            VT[cl * 136 + wr * 64 + m * 16 + lgrp * 4 + r] = f2bf(acc[m][n][r] + bval);
      }
      __syncthreads();
      const int j = (bn - 1024) >> 7;   // 0..3
      const int b = bm >> 11;
      const int sbase = bm & 2047;
      unsigned short* vout = outb + (size_t)2 * 4194304;
#pragma unroll
      for (int q = 0; q < 8; q++) {
        const int chunk = q * 256 + tid;       // 2048 chunks of 8 elems
        const int cl = chunk >> 4, s8 = chunk & 15;
        const int head = 2 * j + (cl >> 6), d = cl & 63;
        ushort8 val = *(const ushort8*)&VT[cl * 136 + s8 * 8];
        *(ushort8*)(vout + ((size_t)(b * 8 + head) * 64 + d) * 2048 + sbase + s8 * 8) = val;
      }
    } else {
      const float qs = (proj == 0) ? 0.18033688011f : 1.0f;  // log2(e)/8
#pragma unroll
      for (int m = 0; m < 4; m++) {
#pragma unroll
        for (int n = 0; n < 4; n++) {
          const int gcol = bn + wc * 64 + n * 16 + lrow;
          const float bval = bias[gcol];
          const int feat = gcol & 511;
          const int head = feat >> 6, d = feat & 63;
#pragma unroll
          for (int r = 0; r < 4; r++) {
            const int grow = bm + wr * 64 + m * 16 + lgrp * 4 + r;
            const int b = grow >> 11, s = grow & 2047;
            const int bh = b * 8 + head;
            outb[(size_t)proj * 4194304 + ((size_t)bh * 2048 + s) * 64 + d] =
                f2bf((acc[m][n][r] + bval) * qs);
          }
        }
      }
    }
  } else {
#pragma unroll
    for (int m = 0; m < 4; m++) {
#pragma unroll
      for (int n = 0; n < 4; n++) {
        const int gcol = bn + wc * 64 + n * 16 + lrow;
        const float bval = bias[gcol];
#pragma unroll
        for (int r = 0; r < 4; r++) {
          const int grow = bm + wr * 64 + m * 16 + lgrp * 4 + r;
          float v = acc[m][n][r] + bval;
          const size_t o = (size_t)grow * N + gcol;
          if constexpr (EPI == 1) {
            outb[o] = f2bf(v + bf2f(residb[o]));
          } else if constexpr (EPI == 2) {
            outb[o] = f2bf(v > 0.f ? v : 0.f);
          } else {
            outf[o] = v + bf2f(residb[o]);
          }
        }
      }
    }
  }
}

// ---------------------------------------------------------------------------
// GEMM 128x64 tile, BK=64, 4 waves (each wave 32 rows x 64 cols).
// EPI 1: bf16 out + bf16 residual; EPI 3: fp32 out + bf16 residual.
// ---------------------------------------------------------------------------
template <int EPI>
__global__ __launch_bounds__(256) void gemm_n64(
    const unsigned short* __restrict__ A, const unsigned short* __restrict__ Bw,
    const float* __restrict__ bias, int M, int N, int K,
    unsigned short* __restrict__ outb, float* __restrict__ outf,
    const unsigned short* __restrict__ residb) {
  __shared__ __align__(16) unsigned short As[128 * 64];
  __shared__ __align__(16) unsigned short Bs[64 * 64];
  const int tid = threadIdx.x;
  const int lane = tid & 63;
  const int wv = tid >> 6;
  const int lrow = lane & 15, lgrp = lane >> 4;
  const int bm = blockIdx.x * 128;
  const int bn = blockIdx.y * 64;

  f32x4 acc[2][4];
#pragma unroll
  for (int m = 0; m < 2; m++)
#pragma unroll
    for (int n = 0; n < 4; n++) acc[m][n] = (f32x4){0.f, 0.f, 0.f, 0.f};

  for (int k0 = 0; k0 < K; k0 += 64) {
    __syncthreads();
#pragma unroll
    for (int i = 0; i < 4; i++) {
      const int sb = wv * 64 + i * 256;
      const int slot = sb + lane;
      const int row = slot >> 3;
      const int cc = (slot & 7) ^ (row & 7);
      gload_lds16(A + (size_t)(bm + row) * K + k0 + cc * 8, &As[sb * 8]);
    }
#pragma unroll
    for (int i = 0; i < 2; i++) {
      const int sb = wv * 64 + i * 256;
      const int slot = sb + lane;
      const int row = slot >> 3;
      const int cc = (slot & 7) ^ (row & 7);
      gload_lds16(Bw + (size_t)(bn + row) * K + k0 + cc * 8, &Bs[sb * 8]);
    }
    __syncthreads();

#pragma unroll
    for (int kk = 0; kk < 2; kk++) {
      short8 af[2], bfr[4];
#pragma unroll
      for (int m = 0; m < 2; m++) {
        const int row = wv * 32 + m * 16 + lrow;
        af[m] = *(const short8*)&As[row * 64 + (((lgrp + 4 * kk) ^ (row & 7)) * 8)];
      }
#pragma unroll
      for (int n = 0; n < 4; n++) {
        const int row = n * 16 + lrow;
        bfr[n] = *(const short8*)&Bs[row * 64 + (((lgrp + 4 * kk) ^ (row & 7)) * 8)];
      }
#pragma unroll
      for (int m = 0; m < 2; m++)
#pragma unroll
        for (int n = 0; n < 4; n++)
          acc[m][n] = __builtin_amdgcn_mfma_f32_16x16x32_bf16(af[m], bfr[n], acc[m][n], 0, 0, 0);
    }
  }

#pragma unroll
  for (int m = 0; m < 2; m++) {
#pragma unroll
    for (int n = 0; n < 4; n++) {
      const int gcol = bn + n * 16 + lrow;
      const float bval = bias[gcol];
#pragma unroll
      for (int r = 0; r < 4; r++) {
        const int grow = bm + wv * 32 + m * 16 + lgrp * 4 + r;
        float v = acc[m][n][r] + bval;
        const size_t o = (size_t)grow * N + gcol;
        if constexpr (EPI == 1) {
          outb[o] = f2bf(v + bf2f(residb[o]));
        } else {
          outf[o] = v + bf2f(residb[o]);
        }
      }
    }
  }
}

// ---------------------------------------------------------------------------
// Flash attention v5: swapped QK^T with 32x32x16 MFMA, fully in-register P.
// Per wave: 32 q-rows (q = lane&31). QK computes mfma(K,Q) so lane holds
// P[k=crow(r,hi)][q=lane&31] (crow=(r&3)+8*(r>>2)+4*hi). exp2 -> cvt_pk pairs
// -> one shfl_xor(32) per 2 words builds PV A-frags in regs (no P LDS).
// PV: B-frag = contiguous rows of V^T tile. lr is lane-local (+1 swap at end).
// 4 waves = 128 q/block, 512 blocks, XCD-chunked. LDS = K tile + V^T tile.
// ---------------------------------------------------------------------------
__global__ __launch_bounds__(256) void attn_k(
    const unsigned short* __restrict__ Qg, const unsigned short* __restrict__ Kg,
    const unsigned short* __restrict__ Vg, unsigned short* __restrict__ Og) {
  __shared__ __align__(16) unsigned short Kl[64 * 64];
  __shared__ __align__(16) unsigned short Vl[64 * 64];
  const int tid = threadIdx.x, lane = tid & 63, wq = tid >> 6;
  const int ql = lane & 31;   // q-column (QK) / d-column (PV)
  const int hi = lane >> 5;
  const int bid = blockIdx.x;
  const int lin = (bid & 7) * 64 + (bid >> 3);
  const int bh = lin >> 4;          // 4 consecutive heads per XCD
  const int q0 = (lin & 15) * 128;  // 128-row q-slab per block
  const int qw = q0 + wq * 32;      // wave's q base
  const size_t hbase = (size_t)bh * (2048 * 64);

  // Q regs: qreg[i] = Q[qw+ql][16i + hi*8 .. +7]  (B-frag for QK mfma #i)
  short8 qreg[4];
  {
    const unsigned short* qp = Qg + hbase + (size_t)(qw + ql) * 64 + hi * 8;
#pragma unroll
    for (int i = 0; i < 4; i++) qreg[i] = *(const short8*)(qp + 16 * i);
  }

  f32x16 oac0 = {0.f, 0.f, 0.f, 0.f, 0.f, 0.f, 0.f, 0.f,
                 0.f, 0.f, 0.f, 0.f, 0.f, 0.f, 0.f, 0.f};
  f32x16 oac1 = oac0;
  float lr = 0.f;

  for (int kt = 0; kt < 2048; kt += 64) {
    __syncthreads();
#pragma unroll
    for (int i = 0; i < 2; i++) {
      const int sb = wq * 64 + i * 256;   // wave-uniform LDS slot base
      const int slot = sb + lane;
      const int r = slot >> 3;
      const int c = (slot & 7) ^ (r & 7);
      gload_lds16(Kg + hbase + (size_t)(kt + r) * 64 + c * 8, &Kl[sb * 8]);
      gload_lds16(Vg + hbase + (size_t)r * 2048 + kt + c * 8, &Vl[sb * 8]);
    }
    __syncthreads();

    // QK^T (swapped): sc0 = K[0:32] x Q, sc1 = K[32:64] x Q
    f32x16 sc0 = {0.f, 0.f, 0.f, 0.f, 0.f, 0.f, 0.f, 0.f,
                  0.f, 0.f, 0.f, 0.f, 0.f, 0.f, 0.f, 0.f};
    f32x16 sc1 = sc0;
    __builtin_amdgcn_s_setprio(1);
#pragma unroll
    for (int i = 0; i < 4; i++) {
      const int c8 = 2 * i + hi;
      const int r0 = ql;
      const int r1 = ql + 32;
      short8 ka = *(const short8*)&Kl[(r0 * 8 + (c8 ^ (r0 & 7))) * 8];
      short8 kb = *(const short8*)&Kl[(r1 * 8 + (c8 ^ (r1 & 7))) * 8];
      sc0 = __builtin_amdgcn_mfma_f32_32x32x16_bf16(ka, qreg[i], sc0, 0, 0, 0);
      sc1 = __builtin_amdgcn_mfma_f32_32x32x16_bf16(kb, qreg[i], sc1, 0, 0, 0);
    }
    __builtin_amdgcn_s_setprio(0);

    // softmax (no-max: Q pre-scaled by log2e/8) + in-register P pack/exchange
    short8 pa[4];
#pragma unroll
    for (int t2 = 0; t2 < 2; t2++) {
      const f32x16& sc = t2 ? sc1 : sc0;
      float p[16];
#pragma unroll
      for (int r = 0; r < 16; r++) {
        p[r] = __builtin_amdgcn_exp2f(sc[r]);
        lr += p[r];
      }
      // groups g: p[4g..4g+3] -> k = 8g + 4hi .. +3 (within 32-tile)
      unsigned w0a = cvtpk(p[0], p[1]),  w0b = cvtpk(p[2], p[3]);
      unsigned w1a = cvtpk(p[4], p[5]),  w1b = cvtpk(p[6], p[7]);
      unsigned w2a = cvtpk(p[8], p[9]),  w2b = cvtpk(p[10], p[11]);
      unsigned w3a = cvtpk(p[12], p[13]), w3b = cvtpk(p[14], p[15]);
      // exchange 1: hi=0 sends g1 (k8-11), hi=1 sends g0 (k4-7)
      unsigned ea = hi ? w0a : w1a, eb = hi ? w0b : w1b;
      unsigned ra = (unsigned)__shfl_xor((int)ea, 32);
      unsigned rb = (unsigned)__shfl_xor((int)eb, 32);
      pa[2 * t2] = hi ? pack4(ra, rb, w1a, w1b) : pack4(w0a, w0b, ra, rb);
      // exchange 2: hi=0 sends g3 (k24-27), hi=1 sends g2 (k20-23)
      ea = hi ? w2a : w3a; eb = hi ? w2b : w3b;
      ra = (unsigned)__shfl_xor((int)ea, 32);
      rb = (unsigned)__shfl_xor((int)eb, 32);
      pa[2 * t2 + 1] = hi ? pack4(ra, rb, w3a, w3b) : pack4(w2a, w2b, ra, rb);
    }

    // PV: O[q][d] += P[q][k] * V[k][d]; B-frag from V^T rows (d fixed per lane)
    __builtin_amdgcn_s_setprio(1);
#pragma unroll
    for (int ks = 0; ks < 4; ks++) {
      const int c8 = 2 * ks + hi;
      const int r0 = ql;
      const int r1 = ql + 32;
      short8 vb0 = *(const short8*)&Vl[(r0 * 8 + (c8 ^ (r0 & 7))) * 8];
      short8 vb1 = *(const short8*)&Vl[(r1 * 8 + (c8 ^ (r1 & 7))) * 8];
      oac0 = __builtin_amdgcn_mfma_f32_32x32x16_bf16(pa[ks], vb0, oac0, 0, 0, 0);
      oac1 = __builtin_amdgcn_mfma_f32_32x32x16_bf16(pa[ks], vb1, oac1, 0, 0, 0);
    }
    __builtin_amdgcn_s_setprio(0);
  }

  // finalize: lane's lr covers half the k-range for q=ql; partner has the rest
  lr += __shfl_xor(lr, 32);
  const float inv = 1.0f / lr;

  const int b = bh >> 3, h = bh & 7;
#pragma unroll
  for (int r = 0; r < 16; r++) {
    const int qrow = (r & 3) + 8 * (r >> 2) + 4 * hi;  // crow(r,hi) = q-local
    const float invr = __shfl(inv, qrow);
    const size_t base = ((size_t)(b * 2048 + qw + qrow)) * 512 + h * 64 + ql;
    Og[base] = f2bf(oac0[r] * invr);
    Og[base + 32] = f2bf(oac1[r] * invr);
  }
}

// ---------------------------------------------------------------------------
// LayerNorm over last dim (512), one wave per token.
// ---------------------------------------------------------------------------
__global__ __launch_bounds__(64) void ln_k(const float* __restrict__ in,
                                           const float* __restrict__ g,
                                           const float* __restrict__ bb,
                                           float* __restrict__ outf) {
  const int row = blockIdx.x, lane = threadIdx.x;
  const float4* p = (const float4*)(in + (size_t)row * 512);
  float4 a = p[lane], b4 = p[lane + 64];
  float s = a.x + a.y + a.z + a.w + b4.x + b4.y + b4.z + b4.w;
#pragma unroll
  for (int off = 32; off >= 1; off >>= 1) s += __shfl_xor(s, off);
  const float mu = s * (1.f / 512.f);
  float q = 0.f;
  {
    float d;
    d = a.x - mu; q += d * d; d = a.y - mu; q += d * d;
    d = a.z - mu; q += d * d; d = a.w - mu; q += d * d;
    d = b4.x - mu; q += d * d; d = b4.y - mu; q += d * d;
    d = b4.z - mu; q += d * d; d = b4.w - mu; q += d * d;
  }
#pragma unroll
  for (int off = 32; off >= 1; off >>= 1) q += __shfl_xor(q, off);
  const float rstd = rsqrtf(q * (1.f / 512.f) + 1e-5f);
  const float4* gp = (const float4*)g;
  const float4* bp = (const float4*)bb;
  float4 g0 = gp[lane], g1 = gp[lane + 64], c0 = bp[lane], c1 = bp[lane + 64];
  float4 o0, o1;
  o0.x = (a.x - mu) * rstd * g0.x + c0.x;
  o0.y = (a.y - mu) * rstd * g0.y + c0.y;
  o0.z = (a.z - mu) * rstd * g0.z + c0.z;
  o0.w = (a.w - mu) * rstd * g0.w + c0.w;
  o1.x = (b4.x - mu) * rstd * g1.x + c1.x;
  o1.y = (b4.y - mu) * rstd * g1.y + c1.y;
  o1.z = (b4.z - mu) * rstd * g1.z + c1.z;
  o1.w = (b4.w - mu) * rstd * g1.w + c1.w;
  float4* of = (float4*)(outf + (size_t)row * 512);
  of[lane] = o0;
  of[lane + 64] = o1;
}

__global__ __launch_bounds__(64) void ln_bf_k(const unsigned short* __restrict__ in,
                                              const float* __restrict__ g,
                                              const float* __restrict__ bb,
                                              unsigned short* __restrict__ out) {
  const int row = blockIdx.x, lane = threadIdx.x;
  ushort8 v = *(const ushort8*)(in + (size_t)row * 512 + lane * 8);
  float f[8];
#pragma unroll
  for (int j = 0; j < 8; j++) f[j] = bf2f(v[j]);
  float s = 0.f;
#pragma unroll
  for (int j = 0; j < 8; j++) s += f[j];
#pragma unroll
  for (int off = 32; off >= 1; off >>= 1) s += __shfl_xor(s, off);
  const float mu = s * (1.f / 512.f);
  float q = 0.f;
#pragma unroll
  for (int j = 0; j < 8; j++) { const float d = f[j] - mu; q += d * d; }
#pragma unroll
  for (int off = 32; off >= 1; off >>= 1) q += __shfl_xor(q, off);
  const float rstd = rsqrtf(q * (1.f / 512.f) + 1e-5f);
  const float4* gp = (const float4*)g;
  const float4* bp = (const float4*)bb;
  float4 g0 = gp[lane * 2], g1 = gp[lane * 2 + 1];
  float4 c0 = bp[lane * 2], c1 = bp[lane * 2 + 1];
  const float gg[8] = {g0.x, g0.y, g0.z, g0.w, g1.x, g1.y, g1.z, g1.w};
  const float cc[8] = {c0.x, c0.y, c0.z, c0.w, c1.x, c1.y, c1.z, c1.w};
  ushort8 ov;
#pragma unroll
  for (int j = 0; j < 8; j++) ov[j] = f2bf((f[j] - mu) * rstd * gg[j] + cc[j]);
  *(ushort8*)(out + (size_t)row * 512 + lane * 8) = ov;
}

// ---------------------------------------------------------------------------
extern "C" void kernel_launch(void* const* d_in, const int* in_sizes, int n_in,
                              void* d_out, int out_size, void* d_ws, size_t ws_size,
                              hipStream_t stream) {
  const float* x = (const float*)d_in[0];
  const float* wq = (const float*)d_in[1];
  const float* bq = (const float*)d_in[2];
  const float* wk = (const float*)d_in[3];
  const float* bk = (const float*)d_in[4];
  const float* wv = (const float*)d_in[5];
  const float* bv = (const float*)d_in[6];
  const float* wo = (const float*)d_in[7];
  const float* bo = (const float*)d_in[8];
  const float* ln_g = (const float*)d_in[9];
  const float* ln_b = (const float*)d_in[10];
  const float* w1 = (const float*)d_in[11];
  const float* b1 = (const float*)d_in[12];
  const float* w2 = (const float*)d_in[13];
  const float* b2 = (const float*)d_in[14];

  // workspace carve-up (ushort elems)
  unsigned short* ws_u = (unsigned short*)d_ws;
  unsigned short* wqkv = ws_u;                   // 786432
  unsigned short* wob = wqkv + 786432;           // 262144
  unsigned short* w1b = wob + 262144;            // 1048576
  unsigned short* w2b = w1b + 1048576;           // 1048576
  unsigned short* xb = w2b + 1048576;            // 4194304  [8192][512]
  unsigned short* qb = xb + 4194304;             // [32][2048][64]
  unsigned short* kb = qb + 4194304;             // [32][2048][64]
  unsigned short* vtb = kb + 4194304;            // V^T [32][64][2048]
  unsigned short* ob = vtb + 4194304;            // attn out [8192][512]
  unsigned short* s1b = ob + 4194304;            // h_pre bf16 [8192][512]
  unsigned short* hb = s1b + 4194304;            // h bf16 [8192][512]
  unsigned short* f1b = qb;                      // reuse qb..ob: [8192][2048]
  float* bqkv = (float*)(hb + 4194304);          // 1536

  // one fused convert launch for all weights + x
  cvt_all_k<<<7168, 256, 0, stream>>>(
      (const float4*)wq, (const float4*)wk, (const float4*)wv, (const float4*)wo,
      (const float4*)w1, (const float4*)w2, (const float4*)x,
      (ushort4v*)wqkv, (ushort4v*)wob, (ushort4v*)w1b, (ushort4v*)w2b,
      (ushort4v*)xb);
  pack_bias_k<<<1, 512, 0, stream>>>(bq, bk, bv, bqkv);

  // QKV projection: M=8192, N=1536, K=512 -> scatter into qb/kb/vtb
  gemm_bt<0><<<dim3(64, 12), 256, 0, stream>>>(xb, wqkv, bqkv, 8192, 1536, 512,
                                               qb, nullptr, nullptr);
  // attention (512 blocks, XCD-chunked internally)
  attn_k<<<512, 256, 0, stream>>>(qb, kb, vtb, ob);
  // O projection + residual(xb): -> s1b bf16   (128x64 tiles -> 512 blocks)
  gemm_n64<1><<<dim3(64, 8), 256, 0, stream>>>(ob, wob, bo, 8192, 512, 512,
                                               s1b, nullptr, xb);
  // LN1 (bf16 -> bf16)
  ln_bf_k<<<8192, 64, 0, stream>>>(s1b, ln_g, ln_b, hb);
  // FFN1 + ReLU: M=8192, N=2048, K=512 -> f1b bf16
  gemm_bt<2><<<dim3(64, 16), 256, 0, stream>>>(hb, w1b, b1, 8192, 2048, 512,
                                               f1b, nullptr, nullptr);
  // FFN2 + residual(hb): M=8192, N=512, K=2048 -> d_out fp32 (128x64 tiles)
  gemm_n64<3><<<dim3(64, 8), 256, 0, stream>>>(f1b, w2b, b2, 8192, 512, 2048,
                                               nullptr, (float*)d_out, hb);
  // LN2 in-place on d_out
  ln_k<<<8192, 64, 0, stream>>>((float*)d_out, ln_g, ln_b, (float*)d_out);
}

// Round 10
// 170.740 us; speedup vs baseline: 1.3769x; 1.0055x over previous
//
#include <hip/hip_runtime.h>

typedef __attribute__((ext_vector_type(8))) short short8;
typedef __attribute__((ext_vector_type(8))) unsigned short ushort8;
typedef __attribute__((ext_vector_type(4))) unsigned short ushort4v;
typedef __attribute__((ext_vector_type(4))) float f32x4;
typedef __attribute__((ext_vector_type(16))) float f32x16;

#define DEV static __device__ __forceinline__

DEV unsigned short f2bf(float f) {
  unsigned u = __builtin_bit_cast(unsigned, f);
  u += 0x7fffu + ((u >> 16) & 1u);
  return (unsigned short)(u >> 16);
}

DEV float bf2f(unsigned short u) {
  return __builtin_bit_cast(float, (unsigned)u << 16);
}

DEV void gload_lds16(const void* g, void* l) {
  __builtin_amdgcn_global_load_lds((__attribute__((address_space(1))) void*)g,
                                   (__attribute__((address_space(3))) void*)l,
                                   16, 0, 0);
}

DEV unsigned cvtpk(float lo, float hi) {
  unsigned u;
  asm("v_cvt_pk_bf16_f32 %0, %1, %2" : "=v"(u) : "v"(lo), "v"(hi));
  return u;
}

// v_permlane32_swap_b32 a, b:  a' = {a.lo, b.lo}, b' = {a.hi, b.hi}
// i.e. lane<32: a'=own a, b'=partner(l+32)'s a; lane>=32: a'=partner's b, b'=own b.
DEV void pl32(unsigned& a, unsigned& b) {
  asm("v_permlane32_swap_b32 %0, %1" : "+v"(a), "+v"(b));
}

DEV short8 pack4(unsigned a, unsigned b, unsigned c, unsigned d) {
  int4 t = make_int4((int)a, (int)b, (int)c, (int)d);
  return __builtin_bit_cast(short8, t);
}

// ---------------------------------------------------------------------------
// fused fp32 -> bf16 convert for all 7 regions in ONE launch.
// ---------------------------------------------------------------------------
__global__ __launch_bounds__(256) void cvt_all_k(
    const float4* __restrict__ wq, const float4* __restrict__ wk,
    const float4* __restrict__ wv, const float4* __restrict__ wo,
    const float4* __restrict__ w1, const float4* __restrict__ w2,
    const float4* __restrict__ x, ushort4v* __restrict__ wqkv,
    ushort4v* __restrict__ wob, ushort4v* __restrict__ w1b,
    ushort4v* __restrict__ w2b, ushort4v* __restrict__ xb) {
  const int i = threadIdx.x;
  const int b = blockIdx.x;
  const float4* s;
  ushort4v* d;
  size_t u;
  if (b < 256)       { s = wq; d = wqkv;          u = (size_t)b * 256 + i; }
  else if (b < 512)  { s = wk; d = wqkv + 65536;  u = (size_t)(b - 256) * 256 + i; }
  else if (b < 768)  { s = wv; d = wqkv + 131072; u = (size_t)(b - 512) * 256 + i; }
  else if (b < 1024) { s = wo; d = wob;           u = (size_t)(b - 768) * 256 + i; }
  else if (b < 2048) { s = w1; d = w1b;           u = (size_t)(b - 1024) * 256 + i; }
  else if (b < 3072) { s = w2; d = w2b;           u = (size_t)(b - 2048) * 256 + i; }
  else               { s = x;  d = xb;            u = (size_t)(b - 3072) * 256 + i; }
  float4 v = s[u];
  ushort4v o = { f2bf(v.x), f2bf(v.y), f2bf(v.z), f2bf(v.w) };
  d[u] = o;
}

__global__ void pack_bias_k(const float* __restrict__ bq, const float* __restrict__ bk,
                            const float* __restrict__ bv, float* __restrict__ o) {
  int i = threadIdx.x;  // 512 threads
  o[i] = bq[i];
  o[512 + i] = bk[i];
  o[1024 + i] = bv[i];
}

// ---------------------------------------------------------------------------
// GEMM 128x128, BK=64, 4 waves. Source-pre-swizzled staging.
// EPI 0: QKV scatter. Q (scaled by log2e/8) -> [bh][s][d], K -> [bh][s][d],
//        V -> TRANSPOSED [bh][d][s] via LDS-transpose (coalesced stores).
// EPI 2: ReLU -> bf16 (outb)
// ---------------------------------------------------------------------------
template <int EPI>
__global__ __launch_bounds__(256) void gemm_bt(
    const unsigned short* __restrict__ A, const unsigned short* __restrict__ Bw,
    const float* __restrict__ bias, int M, int N, int K,
    unsigned short* __restrict__ outb, float* __restrict__ outf,
    const unsigned short* __restrict__ residb) {
  __shared__ __align__(16) unsigned short As[128 * 64];
  __shared__ __align__(16) unsigned short Bs[128 * 64];
  const int tid = threadIdx.x;
  const int lane = tid & 63;
  const int wv = tid >> 6;
  const int wr = wv >> 1, wc = wv & 1;
  const int lrow = lane & 15, lgrp = lane >> 4;
  const int bm = blockIdx.x * 128;
  const int bn = blockIdx.y * 128;

  f32x4 acc[4][4];
#pragma unroll
  for (int m = 0; m < 4; m++)
#pragma unroll
    for (int n = 0; n < 4; n++) acc[m][n] = (f32x4){0.f, 0.f, 0.f, 0.f};

  for (int k0 = 0; k0 < K; k0 += 64) {
    __syncthreads();
#pragma unroll
    for (int i = 0; i < 4; i++) {
      const int sb = wv * 64 + i * 256;   // wave-uniform LDS slot base
      const int slot = sb + lane;
      const int row = slot >> 3;
      const int cc = (slot & 7) ^ (row & 7);   // pre-swizzled source chunk
      gload_lds16(A + (size_t)(bm + row) * K + k0 + cc * 8, &As[sb * 8]);
      gload_lds16(Bw + (size_t)(bn + row) * K + k0 + cc * 8, &Bs[sb * 8]);
    }
    __syncthreads();

#pragma unroll
    for (int kk = 0; kk < 2; kk++) {
      short8 af[4], bfr[4];
#pragma unroll
      for (int m = 0; m < 4; m++) {
        const int row = wr * 64 + m * 16 + lrow;
        af[m] = *(const short8*)&As[row * 64 + (((lgrp + 4 * kk) ^ (row & 7)) * 8)];
      }
#pragma unroll
      for (int n = 0; n < 4; n++) {
        const int row = wc * 64 + n * 16 + lrow;
        bfr[n] = *(const short8*)&Bs[row * 64 + (((lgrp + 4 * kk) ^ (row & 7)) * 8)];
      }
#pragma unroll
      for (int m = 0; m < 4; m++)
#pragma unroll
        for (int n = 0; n < 4; n++)
          acc[m][n] = __builtin_amdgcn_mfma_f32_16x16x32_bf16(af[m], bfr[n], acc[m][n], 0, 0, 0);
    }
  }

  if constexpr (EPI == 0) {
    const int proj = bn >> 9;  // block-uniform: 0=Q, 1=K, 2=V
    if (proj == 2) {
      // --- V: transpose 128x128 tile via LDS, store [bh][d][s] coalesced ---
      __shared__ __align__(16) unsigned short VT[128 * 136];
#pragma unroll
      for (int n = 0; n < 4; n++) {
        const int cl = wc * 64 + n * 16 + lrow;  // local col (d-direction)
        const float bval = bias[bn + cl];
#pragma unroll
        for (int m = 0; m < 4; m++)
#pragma unroll
          for (int r = 0; r < 4; r++)
            VT[cl * 136 + wr * 64 + m * 16 + lgrp * 4 + r] = f2bf(acc[m][n][r] + bval);
      }
      __syncthreads();
      const int j = (bn - 1024) >> 7;   // 0..3
      const int b = bm >> 11;
      const int sbase = bm & 2047;
      unsigned short* vout = outb + (size_t)2 * 4194304;
#pragma unroll
      for (int q = 0; q < 8; q++) {
        const int chunk = q * 256 + tid;       // 2048 chunks of 8 elems
        const int cl = chunk >> 4, s8 = chunk & 15;
        const int head = 2 * j + (cl >> 6), d = cl & 63;
        ushort8 val = *(const ushort8*)&VT[cl * 136 + s8 * 8];
        *(ushort8*)(vout + ((size_t)(b * 8 + head) * 64 + d) * 2048 + sbase + s8 * 8) = val;
      }
    } else {
      const float qs = (proj == 0) ? 0.18033688011f : 1.0f;  // log2(e)/8
#pragma unroll
      for (int m = 0; m < 4; m++) {
#pragma unroll
        for (int n = 0; n < 4; n++) {
          const int gcol = bn + wc * 64 + n * 16 + lrow;
          const float bval = bias[gcol];
          const int feat = gcol & 511;
          const int head = feat >> 6, d = feat & 63;
#pragma unroll
          for (int r = 0; r < 4; r++) {
            const int grow = bm + wr * 64 + m * 16 + lgrp * 4 + r;
            const int b = grow >> 11, s = grow & 2047;
            const int bh = b * 8 + head;
            outb[(size_t)proj * 4194304 + ((size_t)bh * 2048 + s) * 64 + d] =
                f2bf((acc[m][n][r] + bval) * qs);
          }
        }
      }
    }
  } else {
#pragma unroll
    for (int m = 0; m < 4; m++) {
#pragma unroll
      for (int n = 0; n < 4; n++) {
        const int gcol = bn + wc * 64 + n * 16 + lrow;
        const float bval = bias[gcol];
#pragma unroll
        for (int r = 0; r < 4; r++) {
          const int grow = bm + wr * 64 + m * 16 + lgrp * 4 + r;
          float v = acc[m][n][r] + bval;
          const size_t o = (size_t)grow * N + gcol;
          if constexpr (EPI == 1) {
            outb[o] = f2bf(v + bf2f(residb[o]));
          } else if constexpr (EPI == 2) {
            outb[o] = f2bf(v > 0.f ? v : 0.f);
          } else {
            outf[o] = v + bf2f(residb[o]);
          }
        }
      }
    }
  }
}

// ---------------------------------------------------------------------------
// GEMM 128x64 tile, BK=64, 4 waves (each wave 32 rows x 64 cols).
// EPI 1: bf16 out + bf16 residual; EPI 3: fp32 out + bf16 residual.
// ---------------------------------------------------------------------------
template <int EPI>
__global__ __launch_bounds__(256) void gemm_n64(
    const unsigned short* __restrict__ A, const unsigned short* __restrict__ Bw,
    const float* __restrict__ bias, int M, int N, int K,
    unsigned short* __restrict__ outb, float* __restrict__ outf,
    const unsigned short* __restrict__ residb) {
  __shared__ __align__(16) unsigned short As[128 * 64];
  __shared__ __align__(16) unsigned short Bs[64 * 64];
  const int tid = threadIdx.x;
  const int lane = tid & 63;
  const int wv = tid >> 6;
  const int lrow = lane & 15, lgrp = lane >> 4;
  const int bm = blockIdx.x * 128;
  const int bn = blockIdx.y * 64;

  f32x4 acc[2][4];
#pragma unroll
  for (int m = 0; m < 2; m++)
#pragma unroll
    for (int n = 0; n < 4; n++) acc[m][n] = (f32x4){0.f, 0.f, 0.f, 0.f};

  for (int k0 = 0; k0 < K; k0 += 64) {
    __syncthreads();
#pragma unroll
    for (int i = 0; i < 4; i++) {
      const int sb = wv * 64 + i * 256;
      const int slot = sb + lane;
      const int row = slot >> 3;
      const int cc = (slot & 7) ^ (row & 7);
      gload_lds16(A + (size_t)(bm + row) * K + k0 + cc * 8, &As[sb * 8]);
    }
#pragma unroll
    for (int i = 0; i < 2; i++) {
      const int sb = wv * 64 + i * 256;
      const int slot = sb + lane;
      const int row = slot >> 3;
      const int cc = (slot & 7) ^ (row & 7);
      gload_lds16(Bw + (size_t)(bn + row) * K + k0 + cc * 8, &Bs[sb * 8]);
    }
    __syncthreads();

#pragma unroll
    for (int kk = 0; kk < 2; kk++) {
      short8 af[2], bfr[4];
#pragma unroll
      for (int m = 0; m < 2; m++) {
        const int row = wv * 32 + m * 16 + lrow;
        af[m] = *(const short8*)&As[row * 64 + (((lgrp + 4 * kk) ^ (row & 7)) * 8)];
      }
#pragma unroll
      for (int n = 0; n < 4; n++) {
        const int row = n * 16 + lrow;
        bfr[n] = *(const short8*)&Bs[row * 64 + (((lgrp + 4 * kk) ^ (row & 7)) * 8)];
      }
#pragma unroll
      for (int m = 0; m < 2; m++)
#pragma unroll
        for (int n = 0; n < 4; n++)
          acc[m][n] = __builtin_amdgcn_mfma_f32_16x16x32_bf16(af[m], bfr[n], acc[m][n], 0, 0, 0);
    }
  }

#pragma unroll
  for (int m = 0; m < 2; m++) {
#pragma unroll
    for (int n = 0; n < 4; n++) {
      const int gcol = bn + n * 16 + lrow;
      const float bval = bias[gcol];
#pragma unroll
      for (int r = 0; r < 4; r++) {
        const int grow = bm + wv * 32 + m * 16 + lgrp * 4 + r;
        float v = acc[m][n][r] + bval;
        const size_t o = (size_t)grow * N + gcol;
        if constexpr (EPI == 1) {
          outb[o] = f2bf(v + bf2f(residb[o]));
        } else {
          outf[o] = v + bf2f(residb[o]);
        }
      }
    }
  }
}

// ---------------------------------------------------------------------------
// Flash attention v6: swapped QK^T 32x32x16, in-register P via
// permlane32_swap (no LDS round-trip, no cndmask merge), double-buffered
// K/V staging with prefetch-before-compute (1 barrier/tile; grid-limited
// occupancy so the extra LDS is free).
// 4 waves x 32 q-rows = 128 q/block, 512 blocks, XCD-chunked.
// Q,K in [B*NH][2048][64] bf16 (Q pre-scaled by log2e/8); V pre-transposed
// [B*NH][64][2048] bf16. Output [B*2048][512] bf16.
// ---------------------------------------------------------------------------
__global__ __launch_bounds__(256) void attn_k(
    const unsigned short* __restrict__ Qg, const unsigned short* __restrict__ Kg,
    const unsigned short* __restrict__ Vg, unsigned short* __restrict__ Og) {
  __shared__ __align__(16) unsigned short Kl[2][64 * 64];
  __shared__ __align__(16) unsigned short Vl[2][64 * 64];
  const int tid = threadIdx.x, lane = tid & 63, wq = tid >> 6;
  const int ql = lane & 31;   // q-column (QK) / d-column (PV)
  const int hi = lane >> 5;
  const int bid = blockIdx.x;
  const int lin = (bid & 7) * 64 + (bid >> 3);
  const int bh = lin >> 4;          // 4 consecutive heads per XCD
  const int q0 = (lin & 15) * 128;  // 128-row q-slab per block
  const int qw = q0 + wq * 32;      // wave's q base
  const size_t hbase = (size_t)bh * (2048 * 64);

  // staging geometry (loop-invariant per thread)
  const int sb0 = wq * 64, sb1 = wq * 64 + 256;
  const int r0s = (sb0 + lane) >> 3, c0s = ((sb0 + lane) & 7) ^ (r0s & 7);
  const int r1s = (sb1 + lane) >> 3, c1s = ((sb1 + lane) & 7) ^ (r1s & 7);

  // Q regs: qreg[i] = Q[qw+ql][16i + hi*8 .. +7]  (B-frag for QK mfma #i)
  short8 qreg[4];
  {
    const unsigned short* qp = Qg + hbase + (size_t)(qw + ql) * 64 + hi * 8;
#pragma unroll
    for (int i = 0; i < 4; i++) qreg[i] = *(const short8*)(qp + 16 * i);
  }

  f32x16 oac0 = {0.f, 0.f, 0.f, 0.f, 0.f, 0.f, 0.f, 0.f,
                 0.f, 0.f, 0.f, 0.f, 0.f, 0.f, 0.f, 0.f};
  f32x16 oac1 = oac0;
  float lr = 0.f;

  // prologue: stage tile 0 into buffer 0
  gload_lds16(Kg + hbase + (size_t)r0s * 64 + c0s * 8, &Kl[0][sb0 * 8]);
  gload_lds16(Vg + hbase + (size_t)r0s * 2048 + c0s * 8, &Vl[0][sb0 * 8]);
  gload_lds16(Kg + hbase + (size_t)r1s * 64 + c1s * 8, &Kl[0][sb1 * 8]);
  gload_lds16(Vg + hbase + (size_t)r1s * 2048 + c1s * 8, &Vl[0][sb1 * 8]);
  __syncthreads();

  for (int it = 0; it < 32; ++it) {
    const int cur = it & 1;
    if (it < 31) {
      const int kt = (it + 1) * 64;
      const int nxt = cur ^ 1;
      gload_lds16(Kg + hbase + (size_t)(kt + r0s) * 64 + c0s * 8, &Kl[nxt][sb0 * 8]);
      gload_lds16(Vg + hbase + (size_t)r0s * 2048 + kt + c0s * 8, &Vl[nxt][sb0 * 8]);
      gload_lds16(Kg + hbase + (size_t)(kt + r1s) * 64 + c1s * 8, &Kl[nxt][sb1 * 8]);
      gload_lds16(Vg + hbase + (size_t)r1s * 2048 + kt + c1s * 8, &Vl[nxt][sb1 * 8]);
    }

    // QK^T (swapped): sc0 = K[0:32] x Q, sc1 = K[32:64] x Q
    f32x16 sc0 = {0.f, 0.f, 0.f, 0.f, 0.f, 0.f, 0.f, 0.f,
                  0.f, 0.f, 0.f, 0.f, 0.f, 0.f, 0.f, 0.f};
    f32x16 sc1 = sc0;
    __builtin_amdgcn_s_setprio(1);
#pragma unroll
    for (int i = 0; i < 4; i++) {
      const int c8 = 2 * i + hi;
      const int r0 = ql;
      const int r1 = ql + 32;
      short8 ka = *(const short8*)&Kl[cur][(r0 * 8 + (c8 ^ (r0 & 7))) * 8];
      short8 kb = *(const short8*)&Kl[cur][(r1 * 8 + (c8 ^ (r1 & 7))) * 8];
      sc0 = __builtin_amdgcn_mfma_f32_32x32x16_bf16(ka, qreg[i], sc0, 0, 0, 0);
      sc1 = __builtin_amdgcn_mfma_f32_32x32x16_bf16(kb, qreg[i], sc1, 0, 0, 0);
    }
    __builtin_amdgcn_s_setprio(0);

    // softmax (no-max: Q pre-scaled by log2e/8) + in-register P via permlane
    short8 pa[4];
#pragma unroll
    for (int t2 = 0; t2 < 2; t2++) {
      const f32x16& sc = t2 ? sc1 : sc0;
      float p[16];
#pragma unroll
      for (int r = 0; r < 16; r++) {
        p[r] = __builtin_amdgcn_exp2f(sc[r]);
        lr += p[r];
      }
      unsigned w0a = cvtpk(p[0], p[1]),   w0b = cvtpk(p[2], p[3]);
      unsigned w1a = cvtpk(p[4], p[5]),   w1b = cvtpk(p[6], p[7]);
      unsigned w2a = cvtpk(p[8], p[9]),   w2b = cvtpk(p[10], p[11]);
      unsigned w3a = cvtpk(p[12], p[13]), w3b = cvtpk(p[14], p[15]);
      // after pl32(a,b): lane<32: a=own a, b=partner's a;
      //                  lane>=32: a=partner's b, b=own b
      // -> uniform pack for both halves (k 0..7 / 8..15 per A-frag spec)
      pl32(w0a, w1a);
      pl32(w0b, w1b);
      pa[2 * t2] = pack4(w0a, w0b, w1a, w1b);
      pl32(w2a, w3a);
      pl32(w2b, w3b);
      pa[2 * t2 + 1] = pack4(w2a, w2b, w3a, w3b);
    }

    // PV: O[q][d] += P[q][k] * V[k][d]; B-frag from V^T rows (d fixed per lane)
    __builtin_amdgcn_s_setprio(1);
#pragma unroll
    for (int ks = 0; ks < 4; ks++) {
      const int c8 = 2 * ks + hi;
      const int r0 = ql;
      const int r1 = ql + 32;
      short8 vb0 = *(const short8*)&Vl[cur][(r0 * 8 + (c8 ^ (r0 & 7))) * 8];
      short8 vb1 = *(const short8*)&Vl[cur][(r1 * 8 + (c8 ^ (r1 & 7))) * 8];
      oac0 = __builtin_amdgcn_mfma_f32_32x32x16_bf16(pa[ks], vb0, oac0, 0, 0, 0);
      oac1 = __builtin_amdgcn_mfma_f32_32x32x16_bf16(pa[ks], vb1, oac1, 0, 0, 0);
    }
    __builtin_amdgcn_s_setprio(0);

    __syncthreads();  // next-tile loads landed + all waves done with cur
  }

  // finalize: lane's lr covers half the k-range for q=ql; partner has the rest
  lr += __shfl_xor(lr, 32);
  const float inv = 1.0f / lr;

  const int b = bh >> 3, h = bh & 7;
#pragma unroll
  for (int r = 0; r < 16; r++) {
    const int qrow = (r & 3) + 8 * (r >> 2) + 4 * hi;  // crow(r,hi) = q-local
    const float invr = __shfl(inv, qrow);
    const size_t base = ((size_t)(b * 2048 + qw + qrow)) * 512 + h * 64 + ql;
    Og[base] = f2bf(oac0[r] * invr);
    Og[base + 32] = f2bf(oac1[r] * invr);
  }
}

// ---------------------------------------------------------------------------
// LayerNorm over last dim (512), one wave per token.
// ---------------------------------------------------------------------------
__global__ __launch_bounds__(64) void ln_k(const float* __restrict__ in,
                                           const float* __restrict__ g,
                                           const float* __restrict__ bb,
                                           float* __restrict__ outf) {
  const int row = blockIdx.x, lane = threadIdx.x;
  const float4* p = (const float4*)(in + (size_t)row * 512);
  float4 a = p[lane], b4 = p[lane + 64];
  float s = a.x + a.y + a.z + a.w + b4.x + b4.y + b4.z + b4.w;
#pragma unroll
  for (int off = 32; off >= 1; off >>= 1) s += __shfl_xor(s, off);
  const float mu = s * (1.f / 512.f);
  float q = 0.f;
  {
    float d;
    d = a.x - mu; q += d * d; d = a.y - mu; q += d * d;
    d = a.z - mu; q += d * d; d = a.w - mu; q += d * d;
    d = b4.x - mu; q += d * d; d = b4.y - mu; q += d * d;
    d = b4.z - mu; q += d * d; d = b4.w - mu; q += d * d;
  }
#pragma unroll
  for (int off = 32; off >= 1; off >>= 1) q += __shfl_xor(q, off);
  const float rstd = rsqrtf(q * (1.f / 512.f) + 1e-5f);
  const float4* gp = (const float4*)g;
  const float4* bp = (const float4*)bb;
  float4 g0 = gp[lane], g1 = gp[lane + 64], c0 = bp[lane], c1 = bp[lane + 64];
  float4 o0, o1;
  o0.x = (a.x - mu) * rstd * g0.x + c0.x;
  o0.y = (a.y - mu) * rstd * g0.y + c0.y;
  o0.z = (a.z - mu) * rstd * g0.z + c0.z;
  o0.w = (a.w - mu) * rstd * g0.w + c0.w;
  o1.x = (b4.x - mu) * rstd * g1.x + c1.x;
  o1.y = (b4.y - mu) * rstd * g1.y + c1.y;
  o1.z = (b4.z - mu) * rstd * g1.z + c1.z;
  o1.w = (b4.w - mu) * rstd * g1.w + c1.w;
  float4* of = (float4*)(outf + (size_t)row * 512);
  of[lane] = o0;
  of[lane + 64] = o1;
}

__global__ __launch_bounds__(64) void ln_bf_k(const unsigned short* __restrict__ in,
                                              const float* __restrict__ g,
                                              const float* __restrict__ bb,
                                              unsigned short* __restrict__ out) {
  const int row = blockIdx.x, lane = threadIdx.x;
  ushort8 v = *(const ushort8*)(in + (size_t)row * 512 + lane * 8);
  float f[8];
#pragma unroll
  for (int j = 0; j < 8; j++) f[j] = bf2f(v[j]);
  float s = 0.f;
#pragma unroll
  for (int j = 0; j < 8; j++) s += f[j];
#pragma unroll
  for (int off = 32; off >= 1; off >>= 1) s += __shfl_xor(s, off);
  const float mu = s * (1.f / 512.f);
  float q = 0.f;
#pragma unroll
  for (int j = 0; j < 8; j++) { const float d = f[j] - mu; q += d * d; }
#pragma unroll
  for (int off = 32; off >= 1; off >>= 1) q += __shfl_xor(q, off);
  const float rstd = rsqrtf(q * (1.f / 512.f) + 1e-5f);
  const float4* gp = (const float4*)g;
  const float4* bp = (const float4*)bb;
  float4 g0 = gp[lane * 2], g1 = gp[lane * 2 + 1];
  float4 c0 = bp[lane * 2], c1 = bp[lane * 2 + 1];
  const float gg[8] = {g0.x, g0.y, g0.z, g0.w, g1.x, g1.y, g1.z, g1.w};
  const float cc[8] = {c0.x, c0.y, c0.z, c0.w, c1.x, c1.y, c1.z, c1.w};
  ushort8 ov;
#pragma unroll
  for (int j = 0; j < 8; j++) ov[j] = f2bf((f[j] - mu) * rstd * gg[j] + cc[j]);
  *(ushort8*)(out + (size_t)row * 512 + lane * 8) = ov;
}

// ---------------------------------------------------------------------------
extern "C" void kernel_launch(void* const* d_in, const int* in_sizes, int n_in,
                              void* d_out, int out_size, void* d_ws, size_t ws_size,
                              hipStream_t stream) {
  const float* x = (const float*)d_in[0];
  const float* wq = (const float*)d_in[1];
  const float* bq = (const float*)d_in[2];
  const float* wk = (const float*)d_in[3];
  const float* bk = (const float*)d_in[4];
  const float* wv = (const float*)d_in[5];
  const float* bv = (const float*)d_in[6];
  const float* wo = (const float*)d_in[7];
  const float* bo = (const float*)d_in[8];
  const float* ln_g = (const float*)d_in[9];
  const float* ln_b = (const float*)d_in[10];
  const float* w1 = (const float*)d_in[11];
  const float* b1 = (const float*)d_in[12];
  const float* w2 = (const float*)d_in[13];
  const float* b2 = (const float*)d_in[14];

  // workspace carve-up (ushort elems)
  unsigned short* ws_u = (unsigned short*)d_ws;
  unsigned short* wqkv = ws_u;                   // 786432
  unsigned short* wob = wqkv + 786432;           // 262144
  unsigned short* w1b = wob + 262144;            // 1048576
  unsigned short* w2b = w1b + 1048576;           // 1048576
  unsigned short* xb = w2b + 1048576;            // 4194304  [8192][512]
  unsigned short* qb = xb + 4194304;             // [32][2048][64]
  unsigned short* kb = qb + 4194304;             // [32][2048][64]
  unsigned short* vtb = kb + 4194304;            // V^T [32][64][2048]
  unsigned short* ob = vtb + 4194304;            // attn out [8192][512]
  unsigned short* s1b = ob + 4194304;            // h_pre bf16 [8192][512]
  unsigned short* hb = s1b + 4194304;            // h bf16 [8192][512]
  unsigned short* f1b = qb;                      // reuse qb..ob: [8192][2048]
  float* bqkv = (float*)(hb + 4194304);          // 1536

  // one fused convert launch for all weights + x
  cvt_all_k<<<7168, 256, 0, stream>>>(
      (const float4*)wq, (const float4*)wk, (const float4*)wv, (const float4*)wo,
      (const float4*)w1, (const float4*)w2, (const float4*)x,
      (ushort4v*)wqkv, (ushort4v*)wob, (ushort4v*)w1b, (ushort4v*)w2b,
      (ushort4v*)xb);
  pack_bias_k<<<1, 512, 0, stream>>>(bq, bk, bv, bqkv);

  // QKV projection: M=8192, N=1536, K=512 -> scatter into qb/kb/vtb
  gemm_bt<0><<<dim3(64, 12), 256, 0, stream>>>(xb, wqkv, bqkv, 8192, 1536, 512,
                                               qb, nullptr, nullptr);
  // attention (512 blocks, XCD-chunked internally)
  attn_k<<<512, 256, 0, stream>>>(qb, kb, vtb, ob);
  // O projection + residual(xb): -> s1b bf16   (128x64 tiles -> 512 blocks)
  gemm_n64<1><<<dim3(64, 8), 256, 0, stream>>>(ob, wob, bo, 8192, 512, 512,
                                               s1b, nullptr, xb);
  // LN1 (bf16 -> bf16)
  ln_bf_k<<<8192, 64, 0, stream>>>(s1b, ln_g, ln_b, hb);
  // FFN1 + ReLU: M=8192, N=2048, K=512 -> f1b bf16
  gemm_bt<2><<<dim3(64, 16), 256, 0, stream>>>(hb, w1b, b1, 8192, 2048, 512,
                                               f1b, nullptr, nullptr);
  // FFN2 + residual(hb): M=8192, N=512, K=2048 -> d_out fp32 (128x64 tiles)
  gemm_n64<3><<<dim3(64, 8), 256, 0, stream>>>(f1b, w2b, b2, 8192, 512, 2048,
                                               nullptr, (float*)d_out, hb);
  // LN2 in-place on d_out
  ln_k<<<8192, 64, 0, stream>>>((float*)d_out, ln_g, ln_b, (float*)d_out);
}